// Round 4
// baseline (430.263 us; speedup 1.0000x reference)
//
#include <hip/hip_runtime.h>
#include <hip/hip_bf16.h>
#include <math.h>

// Problem constants
#define HIDDEN 1024
#define HEADS  16
#define HDIM   64
#define BATCH  2
#define SEQ    2048
#define ROWS   (BATCH*SEQ)   // 4096
#define BH     (BATCH*HEADS) // 32

typedef __attribute__((ext_vector_type(8))) short  short8;
typedef __attribute__((ext_vector_type(8))) __bf16 bf16x8;
typedef __attribute__((ext_vector_type(4))) float  f32x4;

static __device__ __forceinline__ unsigned short f2bf(float f) {
    unsigned int u = __builtin_bit_cast(unsigned int, f);
    u += 0x7FFFu + ((u >> 16) & 1u);   // round-to-nearest-even
    return (unsigned short)(u >> 16);
}
static __device__ __forceinline__ float bf2f(unsigned short h) {
    unsigned int u = ((unsigned int)h) << 16;
    return __builtin_bit_cast(float, u);
}
static __device__ __forceinline__ f32x4 mfma16(short8 a, short8 b, f32x4 c) {
    return __builtin_amdgcn_mfma_f32_16x16x32_bf16(
        __builtin_bit_cast(bf16x8, a), __builtin_bit_cast(bf16x8, b), c, 0, 0, 0);
}
// async global->LDS, 16B per lane; lds dest = wave-uniform base + lane*16
static __device__ __forceinline__ void gl_lds16(const unsigned short* g, unsigned short* l) {
    __builtin_amdgcn_global_load_lds(
        (const __attribute__((address_space(1))) unsigned int*)g,
        (__attribute__((address_space(3))) unsigned int*)l, 16, 0, 0);
}

// ---------------------------------------------------------------- prep
__global__ void prep_kernel(const float* __restrict__ qp, const float* __restrict__ qa,
                            float* __restrict__ mod, float* __restrict__ posc,
                            float* __restrict__ poss) {
    int i = blockIdx.x * 256 + threadIdx.x;
    if (i < HIDDEN) mod[i] = cosf(qp[i]) * qa[i];
    if (i < SEQ) {
        float ang = (float)i * (6.283185307179586f / (float)SEQ);
        posc[i] = cosf(ang);
        poss[i] = sinf(ang);
    }
}

// ---------------------------------------------------------------- x -> bf16
__global__ void convert_x_kernel(const float* __restrict__ x, unsigned short* __restrict__ xb) {
    int i = (blockIdx.x * 256 + threadIdx.x) * 4;
    float4 v = *(const float4*)(x + i);
    ushort4 o;
    o.x = f2bf(v.x); o.y = f2bf(v.y); o.z = f2bf(v.z); o.w = f2bf(v.w);
    *(ushort4*)(xb + i) = o;
}

// ---------------------------------------------------------------- W -> bf16 transposed  Wt[n][k] = W[k][n]
__global__ __launch_bounds__(256) void transpose_w_kernel(
    const float* __restrict__ w0, const float* __restrict__ w1,
    const float* __restrict__ w2, const float* __restrict__ w3,
    unsigned short* __restrict__ wt) {
    __shared__ unsigned short tile[64][72];
    const float* src = (blockIdx.z == 0) ? w0 : (blockIdx.z == 1) ? w1 : (blockIdx.z == 2) ? w2 : w3;
    unsigned short* dst = wt + (size_t)blockIdx.z * HIDDEN * HIDDEN;
    int n0 = blockIdx.x * 64, k0 = blockIdx.y * 64;
    int t = threadIdx.x;
    int cg = t & 15, r0 = t >> 4;
#pragma unroll
    for (int rr = 0; rr < 4; rr++) {
        int kl = r0 + rr * 16;
        float4 v = *(const float4*)(src + (size_t)(k0 + kl) * HIDDEN + n0 + cg * 4);
        tile[cg*4+0][kl] = f2bf(v.x);
        tile[cg*4+1][kl] = f2bf(v.y);
        tile[cg*4+2][kl] = f2bf(v.z);
        tile[cg*4+3][kl] = f2bf(v.w);
    }
    __syncthreads();
#pragma unroll
    for (int rr = 0; rr < 4; rr++) {
        int nl = r0 + rr * 16;
        ushort4 o;
        o.x = tile[nl][cg*4+0]; o.y = tile[nl][cg*4+1];
        o.z = tile[nl][cg*4+2]; o.w = tile[nl][cg*4+3];
        *(ushort4*)(dst + (size_t)(n0 + nl) * HIDDEN + k0 + cg * 4) = o;
    }
}

// ---------------------------------------------------------------- GEMM (m97 structure)
// C[4096x1024] = A[4096x1024] @ Wt[mode]^T ; async global_load_lds staging, unpadded LDS
__global__ __launch_bounds__(256) void gemm_kernel(
    const unsigned short* __restrict__ A, const unsigned short* __restrict__ WtBase,
    unsigned short* __restrict__ Qp, unsigned short* __restrict__ Kp,
    unsigned short* __restrict__ Vnt, float* __restrict__ Out,
    const float* __restrict__ mod, const float* __restrict__ posc,
    const float* __restrict__ poss, int mode0) {
    __shared__ unsigned short Alds[128 * 32];   // 8KB, [row][32], UNPADDED (global_load_lds)
    __shared__ unsigned short Blds[128 * 32];
    const int mode = mode0 + blockIdx.z;
    const unsigned short* Bt = WtBase + (size_t)mode * HIDDEN * HIDDEN;
    const int m0 = blockIdx.y * 128, n0 = blockIdx.x * 128;
    const int tid = threadIdx.x;
    const int wave = tid >> 6, lane = tid & 63, quad = lane >> 4, l15 = lane & 15;
    const int wr = wave >> 1, wc = wave & 1;
    const int srow = lane >> 2, scol = (lane & 3) * 8;   // staging row/col within 16-row seg

    f32x4 acc[4][4];
    const f32x4 z4 = {0.f, 0.f, 0.f, 0.f};
#pragma unroll
    for (int i = 0; i < 4; i++)
#pragma unroll
        for (int j = 0; j < 4; j++) acc[i][j] = z4;

    for (int k0 = 0; k0 < HIDDEN; k0 += 32) {
        // async staging: wave w covers rows [(w*2+c)*16, +16), lane -> base + lane*16
#pragma unroll
        for (int c = 0; c < 2; c++) {
            int rbase = (wave * 2 + c) * 16;
            gl_lds16(A  + (size_t)(m0 + rbase + srow) * HIDDEN + k0 + scol,
                     &Alds[rbase * 32]);
            gl_lds16(Bt + (size_t)(n0 + rbase + srow) * HIDDEN + k0 + scol,
                     &Blds[rbase * 32]);
        }
        __syncthreads();   // drains vmcnt (compiler emits full waitcnt before barrier)
        short8 aF[4], bF[4];
#pragma unroll
        for (int i = 0; i < 4; i++)
            aF[i] = *(const short8*)(&Alds[(wr * 64 + i * 16 + l15) * 32 + quad * 8]);
#pragma unroll
        for (int j = 0; j < 4; j++)
            bF[j] = *(const short8*)(&Blds[(wc * 64 + j * 16 + l15) * 32 + quad * 8]);
#pragma unroll
        for (int i = 0; i < 4; i++)
#pragma unroll
            for (int j = 0; j < 4; j++)
                acc[i][j] = mfma16(aF[i], bF[j], acc[i][j]);
        __syncthreads();   // all reads done before next iter's async writes land
    }

#pragma unroll
    for (int i = 0; i < 4; i++) {
        int mbase = m0 + wr * 64 + i * 16 + quad * 4;
#pragma unroll
        for (int j = 0; j < 4; j++) {
            int n = n0 + wc * 64 + j * 16 + l15;
#pragma unroll
            for (int r = 0; r < 4; r++) {
                float val = acc[i][j][r];
                int mm = mbase + r;
                if (mode == 3) {
                    Out[(size_t)mm * HIDDEN + n] = val;
                } else {
                    int b = mm >> 11, ss = mm & 2047;
                    int h = n >> 6, d = n & 63;
                    float vm = val * mod[n];
                    if (mode == 0) {
                        size_t base = ((size_t)(b * HEADS + h) * SEQ + ss) * 128;
                        Qp[base + d]      = f2bf(vm * posc[ss] * 0.125f);
                        Qp[base + 64 + d] = f2bf(vm * poss[ss] * 0.125f);
                    } else if (mode == 1) {
                        size_t base = ((size_t)(b * HEADS + h) * SEQ + ss) * 128;
                        Kp[base + d]      = f2bf(vm * posc[ss]);
                        Kp[base + 64 + d] = f2bf(vm * poss[ss]);
                    } else {
                        Vnt[((size_t)(b * HEADS + h) * SEQ + ss) * 64 + d] = f2bf(vm);
                    }
                }
            }
        }
    }
}

// ---------------------------------------------------------------- V shift + transpose
// Vpt[bh][d][s] = (Vnt[bh][s][d] + Vnt[bh][(s+1)%S][d]) / sqrt(2)
__global__ __launch_bounds__(256) void vshift_kernel(const unsigned short* __restrict__ Vnt,
                                                     unsigned short* __restrict__ Vpt) {
    __shared__ unsigned short lds[65][72];
    int bh = blockIdx.y, s0 = blockIdx.x * 64;
    int t = threadIdx.x;
    int cg = t & 15, r0 = t >> 4;
#pragma unroll
    for (int rr = 0; rr < 4; rr++) {
        int row = r0 + rr * 16;
        ushort4 v = *(const ushort4*)(Vnt + ((size_t)bh * SEQ + s0 + row) * 64 + cg * 4);
        *(ushort4*)(&lds[row][cg * 4]) = v;
    }
    if (t < 16) {
        int srow = (s0 + 64) & (SEQ - 1);
        ushort4 v = *(const ushort4*)(Vnt + ((size_t)bh * SEQ + srow) * 64 + t * 4);
        *(ushort4*)(&lds[64][t * 4]) = v;
    }
    __syncthreads();
    int d = t & 63, sb = (t >> 6) * 16;
    unsigned short outv[16];
#pragma unroll
    for (int k = 0; k < 16; k++) {
        float a = bf2f(lds[sb + k][d]), b = bf2f(lds[sb + k + 1][d]);
        outv[k] = f2bf((a + b) * 0.7071067811865476f);
    }
    unsigned short* dst = Vpt + ((size_t)bh * 64 + d) * SEQ + s0 + sb;
#pragma unroll
    for (int k = 0; k < 16; k += 4) {
        ushort4 o; o.x = outv[k]; o.y = outv[k+1]; o.z = outv[k+2]; o.w = outv[k+3];
        *(ushort4*)(dst + k) = o;
    }
}

// ---------------------------------------------------------------- flash attention (no-max softmax)
// Qp/Kp: [bh][s][128] bf16 (pos factors + mod + 1/sqrt(D) folded into Q). Vpt: [bh][d][s] bf16.
// Register-prefetch of next K/V tile overlaps global latency with MFMA+exp of current tile.
#define KT 64
#define KSTR 136   // K row stride (128+8 shorts)
#define VSTR 72    // V^T row stride (64+8 shorts)
#define PSTR 76    // P row stride: quad bank offsets {0,24,16,8} -> <=2-way
__global__ __launch_bounds__(256) void attn_kernel(const unsigned short* __restrict__ Qp,
                                                   const unsigned short* __restrict__ Kp,
                                                   const unsigned short* __restrict__ Vpt,
                                                   unsigned short* __restrict__ Ob) {
    __shared__ unsigned short Klds[KT * KSTR];      // 17408 B
    __shared__ unsigned short Vtlds[64 * VSTR];     // 9216 B
    __shared__ unsigned short Plds[4 * 16 * PSTR];  // 9728 B
    const int bh = blockIdx.y;
    const int tid = threadIdx.x, wave = tid >> 6, lane = tid & 63;
    const int quad = lane >> 4, l15 = lane & 15;
    const int q0 = blockIdx.x * 64 + wave * 16;

    const unsigned short* Qbase = Qp + ((size_t)bh * SEQ + q0 + l15) * 128;
    short8 qf[4];
#pragma unroll
    for (int kk = 0; kk < 4; kk++) qf[kk] = *(const short8*)(Qbase + kk * 32 + quad * 8);

    const f32x4 z4 = {0.f, 0.f, 0.f, 0.f};
    f32x4 acc[4];
#pragma unroll
    for (int dt = 0; dt < 4; dt++) acc[dt] = z4;
    float lsum[4];
#pragma unroll
    for (int r = 0; r < 4; r++) lsum[r] = 0.f;

    unsigned short* pw = &Plds[wave * 16 * PSTR];

    const int krow = tid >> 4, kpart = tid & 15;     // K staging coords (4 chunks/thread)
    const int vrow = tid >> 3, vpart = tid & 7;      // V staging coords (2 chunks/thread)

    uint4 kreg[4], vreg[2];
#pragma unroll
    for (int c = 0; c < 4; c++)
        kreg[c] = *(const uint4*)(Kp + ((size_t)bh * SEQ + (krow + c * 16)) * 128 + kpart * 8);
#pragma unroll
    for (int c = 0; c < 2; c++)
        vreg[c] = *(const uint4*)(Vpt + ((size_t)bh * 64 + (vrow + c * 32)) * SEQ + vpart * 8);

    for (int j0 = 0; j0 < SEQ; j0 += KT) {
        __syncthreads();   // all waves done reading previous tile
#pragma unroll
        for (int c = 0; c < 4; c++)
            *(uint4*)(&Klds[(krow + c * 16) * KSTR + kpart * 8]) = kreg[c];
#pragma unroll
        for (int c = 0; c < 2; c++)
            *(uint4*)(&Vtlds[(vrow + c * 32) * VSTR + vpart * 8]) = vreg[c];
        __syncthreads();   // tile visible

        if (j0 + KT < SEQ) {   // prefetch next tile into registers (latency hidden by compute)
            int jn = j0 + KT;
#pragma unroll
            for (int c = 0; c < 4; c++)
                kreg[c] = *(const uint4*)(Kp + ((size_t)bh * SEQ + jn + krow + c * 16) * 128 + kpart * 8);
#pragma unroll
            for (int c = 0; c < 2; c++)
                vreg[c] = *(const uint4*)(Vpt + ((size_t)bh * 64 + vrow + c * 32) * SEQ + jn + vpart * 8);
        }

        // S = Q K^T over 64 keys (4 subtiles of 16)
        f32x4 sc[4];
#pragma unroll
        for (int t2 = 0; t2 < 4; t2++) {
            sc[t2] = z4;
#pragma unroll
            for (int kk = 0; kk < 4; kk++) {
                short8 kf = *(const short8*)(&Klds[(t2 * 16 + l15) * KSTR + kk * 32 + quad * 8]);
                sc[t2] = mfma16(qf[kk], kf, sc[t2]);
            }
        }

        // P = exp(S), truncation-packed to bf16; lsum accumulates the PACKED value so the
        // truncation bias cancels in the O = num/den ratio.
#pragma unroll
        for (int t2 = 0; t2 < 4; t2++) {
#pragma unroll
            for (int r = 0; r < 4; r++) {
                float p = __expf(sc[t2][r]);
                unsigned short pt = (unsigned short)(__builtin_bit_cast(unsigned int, p) >> 16);
                lsum[r] += bf2f(pt);
                pw[(quad * 4 + r) * PSTR + t2 * 16 + l15] = pt;
            }
        }

        // O += P V'   (P through wave-private LDS: C-layout -> A-layout)
#pragma unroll
        for (int pt = 0; pt < 2; pt++) {
            short8 pa = *(const short8*)(&pw[l15 * PSTR + pt * 32 + quad * 8]);
#pragma unroll
            for (int dt = 0; dt < 4; dt++) {
                short8 vb = *(const short8*)(&Vtlds[(dt * 16 + l15) * VSTR + pt * 32 + quad * 8]);
                acc[dt] = mfma16(pa, vb, acc[dt]);
            }
        }
    }

    float rinv[4];
#pragma unroll
    for (int r = 0; r < 4; r++) {
        float rs = lsum[r];
#pragma unroll
        for (int off = 1; off < 16; off <<= 1) rs += __shfl_xor(rs, off);
        rinv[r] = 1.0f / rs;
    }

    int b = bh >> 4, h = bh & 15;
#pragma unroll
    for (int dt = 0; dt < 4; dt++) {
#pragma unroll
        for (int r = 0; r < 4; r++) {
            int q = q0 + quad * 4 + r;
            int d = dt * 16 + l15;
            Ob[((size_t)(b * SEQ + q)) * HIDDEN + h * 64 + d] = f2bf(acc[dt][r] * rinv[r]);
        }
    }
}

// ---------------------------------------------------------------- launch
extern "C" void kernel_launch(void* const* d_in, const int* in_sizes, int n_in,
                              void* d_out, int out_size, void* d_ws, size_t ws_size,
                              hipStream_t stream) {
    const float* x  = (const float*)d_in[0];
    const float* Wq = (const float*)d_in[1];
    const float* Wk = (const float*)d_in[2];
    const float* Wv = (const float*)d_in[3];
    const float* Wo = (const float*)d_in[4];
    const float* qp = (const float*)d_in[5];
    const float* qa = (const float*)d_in[6];
    char* ws = (char*)d_ws;

    unsigned short* Xb  = (unsigned short*)(ws);                      // 8 MB (reused as Ob)
    unsigned short* Wt  = (unsigned short*)(ws + (size_t)( 8 << 20)); // 8 MB (4 x 2MB, q/k/v/o)
    unsigned short* Qp_ = (unsigned short*)(ws + (size_t)(16 << 20)); // 16 MB
    unsigned short* Kp_ = (unsigned short*)(ws + (size_t)(32 << 20)); // 16 MB
    unsigned short* Vnt = (unsigned short*)(ws + (size_t)(48 << 20)); // 8 MB
    unsigned short* Vpt = (unsigned short*)(ws + (size_t)(56 << 20)); // 8 MB
    float* mod  = (float*)(ws + (size_t)(64 << 20));
    float* posc = mod + 1024;
    float* poss = posc + 2048;
    float* out  = (float*)d_out;

    prep_kernel<<<8, 256, 0, stream>>>(qp, qa, mod, posc, poss);
    convert_x_kernel<<<4096, 256, 0, stream>>>(x, Xb);
    transpose_w_kernel<<<dim3(16, 16, 4), 256, 0, stream>>>(Wq, Wk, Wv, Wo, Wt);
    gemm_kernel<<<dim3(8, 32, 3), 256, 0, stream>>>(Xb, Wt, Qp_, Kp_, Vnt, out,
                                                    mod, posc, poss, 0);
    vshift_kernel<<<dim3(32, 32), 256, 0, stream>>>(Vnt, Vpt);
    attn_kernel<<<dim3(32, 32), 256, 0, stream>>>(Qp_, Kp_, Vpt, Xb /*Ob*/);
    gemm_kernel<<<dim3(8, 32, 1), 256, 0, stream>>>(Xb, Wt, Qp_, Kp_, Vnt, out,
                                                    mod, posc, poss, 3);
}

// Round 5
// 322.269 us; speedup vs baseline: 1.3351x; 1.3351x over previous
//
#include <hip/hip_runtime.h>
#include <hip/hip_bf16.h>
#include <math.h>

// Problem constants
#define HIDDEN 1024
#define HEADS  16
#define HDIM   64
#define BATCH  2
#define SEQ    2048
#define ROWS   (BATCH*SEQ)   // 4096
#define BH     (BATCH*HEADS) // 32

typedef __attribute__((ext_vector_type(8))) short  short8;
typedef __attribute__((ext_vector_type(8))) __bf16 bf16x8;
typedef __attribute__((ext_vector_type(4))) float  f32x4;

static __device__ __forceinline__ unsigned short f2bf(float f) {
    unsigned int u = __builtin_bit_cast(unsigned int, f);
    u += 0x7FFFu + ((u >> 16) & 1u);   // round-to-nearest-even
    return (unsigned short)(u >> 16);
}
static __device__ __forceinline__ float bf2f(unsigned short h) {
    unsigned int u = ((unsigned int)h) << 16;
    return __builtin_bit_cast(float, u);
}
static __device__ __forceinline__ f32x4 mfma16(short8 a, short8 b, f32x4 c) {
    return __builtin_amdgcn_mfma_f32_16x16x32_bf16(
        __builtin_bit_cast(bf16x8, a), __builtin_bit_cast(bf16x8, b), c, 0, 0, 0);
}
// async global->LDS, 16B per lane; lds dest = wave-uniform base + lane*16
static __device__ __forceinline__ void gl_lds16(const unsigned short* g, unsigned short* l) {
    __builtin_amdgcn_global_load_lds(
        (const __attribute__((address_space(1))) unsigned int*)g,
        (__attribute__((address_space(3))) unsigned int*)l, 16, 0, 0);
}

// ---------------------------------------------------------------- prep
__global__ void prep_kernel(const float* __restrict__ qp, const float* __restrict__ qa,
                            float* __restrict__ mod, float* __restrict__ posc,
                            float* __restrict__ poss) {
    int i = blockIdx.x * 256 + threadIdx.x;
    if (i < HIDDEN) mod[i] = cosf(qp[i]) * qa[i];
    if (i < SEQ) {
        float ang = (float)i * (6.283185307179586f / (float)SEQ);
        posc[i] = cosf(ang);
        poss[i] = sinf(ang);
    }
}

// ---------------------------------------------------------------- x -> bf16
__global__ void convert_x_kernel(const float* __restrict__ x, unsigned short* __restrict__ xb) {
    int i = (blockIdx.x * 256 + threadIdx.x) * 4;
    float4 v = *(const float4*)(x + i);
    ushort4 o;
    o.x = f2bf(v.x); o.y = f2bf(v.y); o.z = f2bf(v.z); o.w = f2bf(v.w);
    *(ushort4*)(xb + i) = o;
}

// ---------------------------------------------------------------- W -> bf16 transposed  Wt[n][k] = W[k][n]
__global__ __launch_bounds__(256) void transpose_w_kernel(
    const float* __restrict__ w0, const float* __restrict__ w1,
    const float* __restrict__ w2, const float* __restrict__ w3,
    unsigned short* __restrict__ wt) {
    __shared__ unsigned short tile[64][72];
    const float* src = (blockIdx.z == 0) ? w0 : (blockIdx.z == 1) ? w1 : (blockIdx.z == 2) ? w2 : w3;
    unsigned short* dst = wt + (size_t)blockIdx.z * HIDDEN * HIDDEN;
    int n0 = blockIdx.x * 64, k0 = blockIdx.y * 64;
    int t = threadIdx.x;
    int cg = t & 15, r0 = t >> 4;
#pragma unroll
    for (int rr = 0; rr < 4; rr++) {
        int kl = r0 + rr * 16;
        float4 v = *(const float4*)(src + (size_t)(k0 + kl) * HIDDEN + n0 + cg * 4);
        tile[cg*4+0][kl] = f2bf(v.x);
        tile[cg*4+1][kl] = f2bf(v.y);
        tile[cg*4+2][kl] = f2bf(v.z);
        tile[cg*4+3][kl] = f2bf(v.w);
    }
    __syncthreads();
#pragma unroll
    for (int rr = 0; rr < 4; rr++) {
        int nl = r0 + rr * 16;
        ushort4 o;
        o.x = tile[nl][cg*4+0]; o.y = tile[nl][cg*4+1];
        o.z = tile[nl][cg*4+2]; o.w = tile[nl][cg*4+3];
        *(ushort4*)(dst + (size_t)(n0 + nl) * HIDDEN + k0 + cg * 4) = o;
    }
}

// ---------------------------------------------------------------- GEMM (m97 structure)
// C[4096x1024] = A[4096x1024] @ Wt[mode]^T ; async global_load_lds staging, unpadded LDS
// grid = (mtiles=32, ntiles=8, z): flat id % 8 = mtile % 8 -> the 8 n-tiles sharing an
// A-row-tile land on one XCD (A-tile L2-resident, read 8x from L2 not LLC).
__global__ __launch_bounds__(256) void gemm_kernel(
    const unsigned short* __restrict__ A, const unsigned short* __restrict__ WtBase,
    unsigned short* __restrict__ Qp, unsigned short* __restrict__ Kp,
    unsigned short* __restrict__ Vnt, float* __restrict__ Out,
    const float* __restrict__ mod, const float* __restrict__ posc,
    const float* __restrict__ poss, int mode0) {
    __shared__ unsigned short Alds[128 * 32];   // 8KB, [row][32], UNPADDED (global_load_lds)
    __shared__ unsigned short Blds[128 * 32];
    const int mode = mode0 + blockIdx.z;
    const unsigned short* Bt = WtBase + (size_t)mode * HIDDEN * HIDDEN;
    const int m0 = blockIdx.x * 128, n0 = blockIdx.y * 128;
    const int tid = threadIdx.x;
    const int wave = tid >> 6, lane = tid & 63, quad = lane >> 4, l15 = lane & 15;
    const int wr = wave >> 1, wc = wave & 1;
    const int srow = lane >> 2, scol = (lane & 3) * 8;   // staging row/col within 16-row seg

    f32x4 acc[4][4];
    const f32x4 z4 = {0.f, 0.f, 0.f, 0.f};
#pragma unroll
    for (int i = 0; i < 4; i++)
#pragma unroll
        for (int j = 0; j < 4; j++) acc[i][j] = z4;

    for (int k0 = 0; k0 < HIDDEN; k0 += 32) {
        // async staging: wave w covers rows [(w*2+c)*16, +16), lane -> base + lane*16
#pragma unroll
        for (int c = 0; c < 2; c++) {
            int rbase = (wave * 2 + c) * 16;
            gl_lds16(A  + (size_t)(m0 + rbase + srow) * HIDDEN + k0 + scol,
                     &Alds[rbase * 32]);
            gl_lds16(Bt + (size_t)(n0 + rbase + srow) * HIDDEN + k0 + scol,
                     &Blds[rbase * 32]);
        }
        __syncthreads();   // drains vmcnt (compiler emits full waitcnt before barrier)
        short8 aF[4], bF[4];
#pragma unroll
        for (int i = 0; i < 4; i++)
            aF[i] = *(const short8*)(&Alds[(wr * 64 + i * 16 + l15) * 32 + quad * 8]);
#pragma unroll
        for (int j = 0; j < 4; j++)
            bF[j] = *(const short8*)(&Blds[(wc * 64 + j * 16 + l15) * 32 + quad * 8]);
#pragma unroll
        for (int i = 0; i < 4; i++)
#pragma unroll
            for (int j = 0; j < 4; j++)
                acc[i][j] = mfma16(aF[i], bF[j], acc[i][j]);
        __syncthreads();   // all reads done before next iter's async writes land
    }

#pragma unroll
    for (int i = 0; i < 4; i++) {
        int mbase = m0 + wr * 64 + i * 16 + quad * 4;
#pragma unroll
        for (int j = 0; j < 4; j++) {
            int n = n0 + wc * 64 + j * 16 + l15;
#pragma unroll
            for (int r = 0; r < 4; r++) {
                float val = acc[i][j][r];
                int mm = mbase + r;
                if (mode == 3) {
                    Out[(size_t)mm * HIDDEN + n] = val;
                } else {
                    int b = mm >> 11, ss = mm & 2047;
                    int h = n >> 6, d = n & 63;
                    float vm = val * mod[n];
                    if (mode == 0) {
                        size_t base = ((size_t)(b * HEADS + h) * SEQ + ss) * 128;
                        Qp[base + d]      = f2bf(vm * posc[ss] * 0.125f);
                        Qp[base + 64 + d] = f2bf(vm * poss[ss] * 0.125f);
                    } else if (mode == 1) {
                        size_t base = ((size_t)(b * HEADS + h) * SEQ + ss) * 128;
                        Kp[base + d]      = f2bf(vm * posc[ss]);
                        Kp[base + 64 + d] = f2bf(vm * poss[ss]);
                    } else {
                        Vnt[((size_t)(b * HEADS + h) * SEQ + ss) * 64 + d] = f2bf(vm);
                    }
                }
            }
        }
    }
}

// ---------------------------------------------------------------- V shift + transpose
// Vpt[bh][d][s] = (Vnt[bh][s][d] + Vnt[bh][(s+1)%S][d]) / sqrt(2)
// grid = (bh=32, stile=32): flat id % 8 = bh % 8 -> same XCD as attn's consumer of Vpt[bh]
__global__ __launch_bounds__(256) void vshift_kernel(const unsigned short* __restrict__ Vnt,
                                                     unsigned short* __restrict__ Vpt) {
    __shared__ unsigned short lds[65][72];
    int bh = blockIdx.x, s0 = blockIdx.y * 64;
    int t = threadIdx.x;
    int cg = t & 15, r0 = t >> 4;
#pragma unroll
    for (int rr = 0; rr < 4; rr++) {
        int row = r0 + rr * 16;
        ushort4 v = *(const ushort4*)(Vnt + ((size_t)bh * SEQ + s0 + row) * 64 + cg * 4);
        *(ushort4*)(&lds[row][cg * 4]) = v;
    }
    if (t < 16) {
        int srow = (s0 + 64) & (SEQ - 1);
        ushort4 v = *(const ushort4*)(Vnt + ((size_t)bh * SEQ + srow) * 64 + t * 4);
        *(ushort4*)(&lds[64][t * 4]) = v;
    }
    __syncthreads();
    int d = t & 63, sb = (t >> 6) * 16;
    unsigned short outv[16];
#pragma unroll
    for (int k = 0; k < 16; k++) {
        float a = bf2f(lds[sb + k][d]), b = bf2f(lds[sb + k + 1][d]);
        outv[k] = f2bf((a + b) * 0.7071067811865476f);
    }
    unsigned short* dst = Vpt + ((size_t)bh * 64 + d) * SEQ + s0 + sb;
#pragma unroll
    for (int k = 0; k < 16; k += 4) {
        ushort4 o; o.x = outv[k]; o.y = outv[k+1]; o.z = outv[k+2]; o.w = outv[k+3];
        *(ushort4*)(dst + k) = o;
    }
}

// ---------------------------------------------------------------- flash attention (no-max softmax)
// Qp/Kp: [bh][s][128] bf16 (pos factors + mod + 1/sqrt(D) folded into Q). Vpt: [bh][d][s] bf16.
// grid = (bh=32, qtile=32): flat id % 8 = bh % 8 -> all 32 q-tiles of head bh on XCD bh%8;
// per-XCD K/V working set = 4 heads x 768 KB = 3 MB < 4 MB L2 -> K/V re-reads are local L2 hits.
#define KT 64
#define KSTR 136   // K row stride (128+8 shorts)
#define VSTR 72    // V^T row stride (64+8 shorts)
#define PSTR 76    // P row stride: quad bank offsets {0,24,16,8} -> <=2-way
__global__ __launch_bounds__(256) void attn_kernel(const unsigned short* __restrict__ Qp,
                                                   const unsigned short* __restrict__ Kp,
                                                   const unsigned short* __restrict__ Vpt,
                                                   unsigned short* __restrict__ Ob) {
    __shared__ unsigned short Klds[KT * KSTR];      // 17408 B
    __shared__ unsigned short Vtlds[64 * VSTR];     // 9216 B
    __shared__ unsigned short Plds[4 * 16 * PSTR];  // 9728 B
    const int bh = blockIdx.x;
    const int tid = threadIdx.x, wave = tid >> 6, lane = tid & 63;
    const int quad = lane >> 4, l15 = lane & 15;
    const int q0 = blockIdx.y * 64 + wave * 16;

    const unsigned short* Qbase = Qp + ((size_t)bh * SEQ + q0 + l15) * 128;
    short8 qf[4];
#pragma unroll
    for (int kk = 0; kk < 4; kk++) qf[kk] = *(const short8*)(Qbase + kk * 32 + quad * 8);

    const f32x4 z4 = {0.f, 0.f, 0.f, 0.f};
    f32x4 acc[4];
#pragma unroll
    for (int dt = 0; dt < 4; dt++) acc[dt] = z4;
    float lsum[4];
#pragma unroll
    for (int r = 0; r < 4; r++) lsum[r] = 0.f;

    unsigned short* pw = &Plds[wave * 16 * PSTR];

    for (int j0 = 0; j0 < SEQ; j0 += KT) {
        __syncthreads();
#pragma unroll
        for (int s2 = tid; s2 < KT * 16; s2 += 256) {      // K: 64 rows x 128 shorts
            int row = s2 >> 4, part = s2 & 15;
            *(uint4*)(&Klds[row * KSTR + part * 8]) =
                *(const uint4*)(Kp + ((size_t)bh * SEQ + j0 + row) * 128 + part * 8);
        }
#pragma unroll
        for (int s2 = tid; s2 < 64 * 8; s2 += 256) {       // V^T: 64 d-rows x 64 keys
            int row = s2 >> 3, part = s2 & 7;
            *(uint4*)(&Vtlds[row * VSTR + part * 8]) =
                *(const uint4*)(Vpt + ((size_t)bh * 64 + row) * SEQ + j0 + part * 8);
        }
        __syncthreads();

        // S = Q K^T over 64 keys (4 subtiles of 16)
        f32x4 sc[4];
#pragma unroll
        for (int t2 = 0; t2 < 4; t2++) {
            sc[t2] = z4;
#pragma unroll
            for (int kk = 0; kk < 4; kk++) {
                short8 kf = *(const short8*)(&Klds[(t2 * 16 + l15) * KSTR + kk * 32 + quad * 8]);
                sc[t2] = mfma16(qf[kk], kf, sc[t2]);
            }
        }

        // P = exp(S), truncation-packed to bf16; lsum accumulates the PACKED value so the
        // truncation bias cancels in the O = num/den ratio.
#pragma unroll
        for (int t2 = 0; t2 < 4; t2++) {
#pragma unroll
            for (int r = 0; r < 4; r++) {
                float p = __expf(sc[t2][r]);
                unsigned short pt = (unsigned short)(__builtin_bit_cast(unsigned int, p) >> 16);
                lsum[r] += bf2f(pt);
                pw[(quad * 4 + r) * PSTR + t2 * 16 + l15] = pt;
            }
        }

        // O += P V'   (P through wave-private LDS: C-layout -> A-layout)
#pragma unroll
        for (int pt = 0; pt < 2; pt++) {
            short8 pa = *(const short8*)(&pw[l15 * PSTR + pt * 32 + quad * 8]);
#pragma unroll
            for (int dt = 0; dt < 4; dt++) {
                short8 vb = *(const short8*)(&Vtlds[(dt * 16 + l15) * VSTR + pt * 32 + quad * 8]);
                acc[dt] = mfma16(pa, vb, acc[dt]);
            }
        }
    }

    float rinv[4];
#pragma unroll
    for (int r = 0; r < 4; r++) {
        float rs = lsum[r];
#pragma unroll
        for (int off = 1; off < 16; off <<= 1) rs += __shfl_xor(rs, off);
        rinv[r] = 1.0f / rs;
    }

    int b = bh >> 4, h = bh & 15;
#pragma unroll
    for (int dt = 0; dt < 4; dt++) {
#pragma unroll
        for (int r = 0; r < 4; r++) {
            int q = q0 + quad * 4 + r;
            int d = dt * 16 + l15;
            Ob[((size_t)(b * SEQ + q)) * HIDDEN + h * 64 + d] = f2bf(acc[dt][r] * rinv[r]);
        }
    }
}

// ---------------------------------------------------------------- launch
extern "C" void kernel_launch(void* const* d_in, const int* in_sizes, int n_in,
                              void* d_out, int out_size, void* d_ws, size_t ws_size,
                              hipStream_t stream) {
    const float* x  = (const float*)d_in[0];
    const float* Wq = (const float*)d_in[1];
    const float* Wk = (const float*)d_in[2];
    const float* Wv = (const float*)d_in[3];
    const float* Wo = (const float*)d_in[4];
    const float* qp = (const float*)d_in[5];
    const float* qa = (const float*)d_in[6];
    char* ws = (char*)d_ws;

    unsigned short* Xb  = (unsigned short*)(ws);                      // 8 MB (reused as Ob)
    unsigned short* Wt  = (unsigned short*)(ws + (size_t)( 8 << 20)); // 8 MB (4 x 2MB, q/k/v/o)
    unsigned short* Qp_ = (unsigned short*)(ws + (size_t)(16 << 20)); // 16 MB
    unsigned short* Kp_ = (unsigned short*)(ws + (size_t)(32 << 20)); // 16 MB
    unsigned short* Vnt = (unsigned short*)(ws + (size_t)(48 << 20)); // 8 MB
    unsigned short* Vpt = (unsigned short*)(ws + (size_t)(56 << 20)); // 8 MB
    float* mod  = (float*)(ws + (size_t)(64 << 20));
    float* posc = mod + 1024;
    float* poss = posc + 2048;
    float* out  = (float*)d_out;

    prep_kernel<<<8, 256, 0, stream>>>(qp, qa, mod, posc, poss);
    convert_x_kernel<<<4096, 256, 0, stream>>>(x, Xb);
    transpose_w_kernel<<<dim3(16, 16, 4), 256, 0, stream>>>(Wq, Wk, Wv, Wo, Wt);
    gemm_kernel<<<dim3(32, 8, 3), 256, 0, stream>>>(Xb, Wt, Qp_, Kp_, Vnt, out,
                                                    mod, posc, poss, 0);
    vshift_kernel<<<dim3(32, 32), 256, 0, stream>>>(Vnt, Vpt);
    attn_kernel<<<dim3(32, 32), 256, 0, stream>>>(Qp_, Kp_, Vpt, Xb /*Ob*/);
    gemm_kernel<<<dim3(32, 8, 1), 256, 0, stream>>>(Xb, Wt, Qp_, Kp_, Vnt, out,
                                                    mod, posc, poss, 3);
}

// Round 6
// 311.406 us; speedup vs baseline: 1.3817x; 1.0349x over previous
//
#include <hip/hip_runtime.h>
#include <hip/hip_bf16.h>
#include <math.h>

// Problem constants
#define HIDDEN 1024
#define HEADS  16
#define HDIM   64
#define BATCH  2
#define SEQ    2048
#define ROWS   (BATCH*SEQ)   // 4096
#define BH     (BATCH*HEADS) // 32

typedef __attribute__((ext_vector_type(8))) short  short8;
typedef __attribute__((ext_vector_type(8))) __bf16 bf16x8;
typedef __attribute__((ext_vector_type(4))) float  f32x4;

static __device__ __forceinline__ unsigned short f2bf(float f) {
    unsigned int u = __builtin_bit_cast(unsigned int, f);
    u += 0x7FFFu + ((u >> 16) & 1u);   // round-to-nearest-even
    return (unsigned short)(u >> 16);
}
static __device__ __forceinline__ float bf2f(unsigned short h) {
    unsigned int u = ((unsigned int)h) << 16;
    return __builtin_bit_cast(float, u);
}
static __device__ __forceinline__ f32x4 mfma16(short8 a, short8 b, f32x4 c) {
    return __builtin_amdgcn_mfma_f32_16x16x32_bf16(
        __builtin_bit_cast(bf16x8, a), __builtin_bit_cast(bf16x8, b), c, 0, 0, 0);
}
// async global->LDS, 16B per lane; lds dest = wave-uniform base + lane*16
static __device__ __forceinline__ void gl_lds16(const unsigned short* g, unsigned short* l) {
    __builtin_amdgcn_global_load_lds(
        (const __attribute__((address_space(1))) unsigned int*)g,
        (__attribute__((address_space(3))) unsigned int*)l, 16, 0, 0);
}

// ---------------------------------------------------------------- prep
__global__ void prep_kernel(const float* __restrict__ qp, const float* __restrict__ qa,
                            float* __restrict__ mod, float* __restrict__ posc,
                            float* __restrict__ poss) {
    int i = blockIdx.x * 256 + threadIdx.x;
    if (i < HIDDEN) mod[i] = cosf(qp[i]) * qa[i];
    if (i < SEQ) {
        float ang = (float)i * (6.283185307179586f / (float)SEQ);
        posc[i] = cosf(ang);
        poss[i] = sinf(ang);
    }
}

// ---------------------------------------------------------------- x -> bf16
__global__ void convert_x_kernel(const float* __restrict__ x, unsigned short* __restrict__ xb) {
    int i = (blockIdx.x * 256 + threadIdx.x) * 4;
    float4 v = *(const float4*)(x + i);
    ushort4 o;
    o.x = f2bf(v.x); o.y = f2bf(v.y); o.z = f2bf(v.z); o.w = f2bf(v.w);
    *(ushort4*)(xb + i) = o;
}

// ---------------------------------------------------------------- W -> bf16 transposed  Wt[n][k] = W[k][n]
__global__ __launch_bounds__(256) void transpose_w_kernel(
    const float* __restrict__ w0, const float* __restrict__ w1,
    const float* __restrict__ w2, const float* __restrict__ w3,
    unsigned short* __restrict__ wt) {
    __shared__ unsigned short tile[64][72];
    const float* src = (blockIdx.z == 0) ? w0 : (blockIdx.z == 1) ? w1 : (blockIdx.z == 2) ? w2 : w3;
    unsigned short* dst = wt + (size_t)blockIdx.z * HIDDEN * HIDDEN;
    int n0 = blockIdx.x * 64, k0 = blockIdx.y * 64;
    int t = threadIdx.x;
    int cg = t & 15, r0 = t >> 4;
#pragma unroll
    for (int rr = 0; rr < 4; rr++) {
        int kl = r0 + rr * 16;
        float4 v = *(const float4*)(src + (size_t)(k0 + kl) * HIDDEN + n0 + cg * 4);
        tile[cg*4+0][kl] = f2bf(v.x);
        tile[cg*4+1][kl] = f2bf(v.y);
        tile[cg*4+2][kl] = f2bf(v.z);
        tile[cg*4+3][kl] = f2bf(v.w);
    }
    __syncthreads();
#pragma unroll
    for (int rr = 0; rr < 4; rr++) {
        int nl = r0 + rr * 16;
        ushort4 o;
        o.x = tile[nl][cg*4+0]; o.y = tile[nl][cg*4+1];
        o.z = tile[nl][cg*4+2]; o.w = tile[nl][cg*4+3];
        *(ushort4*)(dst + (size_t)(n0 + nl) * HIDDEN + k0 + cg * 4) = o;
    }
}

// ---------------------------------------------------------------- GEMM (m97 structure)
// grid = (mtiles=32, ntiles=8, z): flat id % 8 = mtile % 8 -> the 8 n-tiles sharing an
// A-row-tile land on one XCD (A-tile L2-resident).
__global__ __launch_bounds__(256) void gemm_kernel(
    const unsigned short* __restrict__ A, const unsigned short* __restrict__ WtBase,
    unsigned short* __restrict__ Qp, unsigned short* __restrict__ Kp,
    unsigned short* __restrict__ Vnt, float* __restrict__ Out,
    const float* __restrict__ mod, const float* __restrict__ posc,
    const float* __restrict__ poss, int mode0) {
    __shared__ unsigned short Alds[128 * 32];   // 8KB, [row][32], UNPADDED (global_load_lds)
    __shared__ unsigned short Blds[128 * 32];
    const int mode = mode0 + blockIdx.z;
    const unsigned short* Bt = WtBase + (size_t)mode * HIDDEN * HIDDEN;
    const int m0 = blockIdx.x * 128, n0 = blockIdx.y * 128;
    const int tid = threadIdx.x;
    const int wave = tid >> 6, lane = tid & 63, quad = lane >> 4, l15 = lane & 15;
    const int wr = wave >> 1, wc = wave & 1;
    const int srow = lane >> 2, scol = (lane & 3) * 8;

    f32x4 acc[4][4];
    const f32x4 z4 = {0.f, 0.f, 0.f, 0.f};
#pragma unroll
    for (int i = 0; i < 4; i++)
#pragma unroll
        for (int j = 0; j < 4; j++) acc[i][j] = z4;

    for (int k0 = 0; k0 < HIDDEN; k0 += 32) {
#pragma unroll
        for (int c = 0; c < 2; c++) {
            int rbase = (wave * 2 + c) * 16;
            gl_lds16(A  + (size_t)(m0 + rbase + srow) * HIDDEN + k0 + scol,
                     &Alds[rbase * 32]);
            gl_lds16(Bt + (size_t)(n0 + rbase + srow) * HIDDEN + k0 + scol,
                     &Blds[rbase * 32]);
        }
        __syncthreads();
        short8 aF[4], bF[4];
#pragma unroll
        for (int i = 0; i < 4; i++)
            aF[i] = *(const short8*)(&Alds[(wr * 64 + i * 16 + l15) * 32 + quad * 8]);
#pragma unroll
        for (int j = 0; j < 4; j++)
            bF[j] = *(const short8*)(&Blds[(wc * 64 + j * 16 + l15) * 32 + quad * 8]);
#pragma unroll
        for (int i = 0; i < 4; i++)
#pragma unroll
            for (int j = 0; j < 4; j++)
                acc[i][j] = mfma16(aF[i], bF[j], acc[i][j]);
        __syncthreads();
    }

#pragma unroll
    for (int i = 0; i < 4; i++) {
        int mbase = m0 + wr * 64 + i * 16 + quad * 4;
#pragma unroll
        for (int j = 0; j < 4; j++) {
            int n = n0 + wc * 64 + j * 16 + l15;
#pragma unroll
            for (int r = 0; r < 4; r++) {
                float val = acc[i][j][r];
                int mm = mbase + r;
                if (mode == 3) {
                    Out[(size_t)mm * HIDDEN + n] = val;
                } else {
                    int b = mm >> 11, ss = mm & 2047;
                    int h = n >> 6, d = n & 63;
                    float vm = val * mod[n];
                    if (mode == 0) {
                        size_t base = ((size_t)(b * HEADS + h) * SEQ + ss) * 128;
                        Qp[base + d]      = f2bf(vm * posc[ss] * 0.125f);
                        Qp[base + 64 + d] = f2bf(vm * poss[ss] * 0.125f);
                    } else if (mode == 1) {
                        size_t base = ((size_t)(b * HEADS + h) * SEQ + ss) * 128;
                        Kp[base + d]      = f2bf(vm * posc[ss]);
                        Kp[base + 64 + d] = f2bf(vm * poss[ss]);
                    } else {
                        Vnt[((size_t)(b * HEADS + h) * SEQ + ss) * 64 + d] = f2bf(vm);
                    }
                }
            }
        }
    }
}

// ---------------------------------------------------------------- V shift + transpose
// grid = (bh=32, stile=32): bh fast -> same XCD as attn's consumer of Vpt[bh]
__global__ __launch_bounds__(256) void vshift_kernel(const unsigned short* __restrict__ Vnt,
                                                     unsigned short* __restrict__ Vpt) {
    __shared__ unsigned short lds[65][72];
    int bh = blockIdx.x, s0 = blockIdx.y * 64;
    int t = threadIdx.x;
    int cg = t & 15, r0 = t >> 4;
#pragma unroll
    for (int rr = 0; rr < 4; rr++) {
        int row = r0 + rr * 16;
        ushort4 v = *(const ushort4*)(Vnt + ((size_t)bh * SEQ + s0 + row) * 64 + cg * 4);
        *(ushort4*)(&lds[row][cg * 4]) = v;
    }
    if (t < 16) {
        int srow = (s0 + 64) & (SEQ - 1);
        ushort4 v = *(const ushort4*)(Vnt + ((size_t)bh * SEQ + srow) * 64 + t * 4);
        *(ushort4*)(&lds[64][t * 4]) = v;
    }
    __syncthreads();
    int d = t & 63, sb = (t >> 6) * 16;
    unsigned short outv[16];
#pragma unroll
    for (int k = 0; k < 16; k++) {
        float a = bf2f(lds[sb + k][d]), b = bf2f(lds[sb + k + 1][d]);
        outv[k] = f2bf((a + b) * 0.7071067811865476f);
    }
    unsigned short* dst = Vpt + ((size_t)bh * 64 + d) * SEQ + s0 + sb;
#pragma unroll
    for (int k = 0; k < 16; k += 4) {
        ushort4 o; o.x = outv[k]; o.y = outv[k+1]; o.z = outv[k+2]; o.w = outv[k+3];
        *(ushort4*)(dst + k) = o;
    }
}

// ---------------------------------------------------------------- flash attention
// Double-buffered async K/V staging via global_load_lds (one barrier per K-tile),
// XOR chunk swizzle on the global-source side so unpadded LDS fragment reads are
// conflict-free: K chunk' = chunk ^ (row&15), V chunk' = chunk ^ (row&7).
// grid = (bh=32, qtile=32): bh fast -> head's K/V pinned to one XCD's L2.
#define KT 64
#define PSTR 76    // P row stride: quad bank offsets {0,24,16,8} -> <=2-way
__global__ __launch_bounds__(256) void attn_kernel(const unsigned short* __restrict__ Qp,
                                                   const unsigned short* __restrict__ Kp,
                                                   const unsigned short* __restrict__ Vpt,
                                                   unsigned short* __restrict__ Ob) {
    __shared__ unsigned short Klds[2][KT * 128];    // 2 x 16 KB, unpadded
    __shared__ unsigned short Vtlds[2][64 * 64];    // 2 x 8 KB, unpadded
    __shared__ unsigned short Plds[4 * 16 * PSTR];  // 9728 B
    const int bh = blockIdx.x;
    const int tid = threadIdx.x, wave = tid >> 6, lane = tid & 63;
    const int quad = lane >> 4, l15 = lane & 15;
    const int q0 = blockIdx.y * 64 + wave * 16;

    const unsigned short* Qbase = Qp + ((size_t)bh * SEQ + q0 + l15) * 128;
    short8 qf[4];
#pragma unroll
    for (int kk = 0; kk < 4; kk++) qf[kk] = *(const short8*)(Qbase + kk * 32 + quad * 8);

    const f32x4 z4 = {0.f, 0.f, 0.f, 0.f};
    f32x4 acc[4];
#pragma unroll
    for (int dt = 0; dt < 4; dt++) acc[dt] = z4;
    float lsum[4];
#pragma unroll
    for (int r = 0; r < 4; r++) lsum[r] = 0.f;

    unsigned short* pw = &Plds[wave * 16 * PSTR];

    const unsigned short* Kbh = Kp  + (size_t)bh * SEQ * 128;
    const unsigned short* Vbh = Vpt + (size_t)bh * 64 * SEQ;

    // stage tile at key offset j into buffer buf (async; lands by next barrier)
    auto stage = [&](int j, int buf) {
#pragma unroll
        for (int p = 0; p < 4; p++) {               // K: 4 passes of 16 rows
            int rb = p * 16 + wave * 4;             // wave-uniform base row
            int r  = rb + (lane >> 4);
            int c  = (lane & 15) ^ (r & 15);        // swizzled source chunk
            gl_lds16(Kbh + (size_t)(j + r) * 128 + c * 8, &Klds[buf][rb * 128]);
        }
#pragma unroll
        for (int p = 0; p < 2; p++) {               // V^T: 2 passes of 32 d-rows
            int rb = p * 32 + wave * 8;
            int r  = rb + (lane >> 3);
            int c  = (lane & 7) ^ (r & 7);
            gl_lds16(Vbh + (size_t)r * SEQ + j + c * 8, &Vtlds[buf][rb * 64]);
        }
    };

    stage(0, 0);
    for (int it = 0; it < SEQ / KT; it++) {
        __syncthreads();                 // drains tile `it` loads; prev buf reads done
        if (it + 1 < SEQ / KT) stage((it + 1) * KT, (it + 1) & 1);   // overlap w/ compute
        const int buf = it & 1;

        // S = Q K^T over 64 keys (4 subtiles of 16); swizzled K reads (conflict-free)
        f32x4 sc[4];
#pragma unroll
        for (int t2 = 0; t2 < 4; t2++) {
            sc[t2] = z4;
#pragma unroll
            for (int kk = 0; kk < 4; kk++) {
                int ch = (kk * 4 + quad) ^ l15;     // row&15 == l15
                short8 kf = *(const short8*)(&Klds[buf][(t2 * 16 + l15) * 128 + ch * 8]);
                sc[t2] = mfma16(qf[kk], kf, sc[t2]);
            }
        }

        // P = exp(S), truncation-packed to bf16; lsum accumulates the PACKED value so the
        // truncation bias cancels in the O = num/den ratio.
#pragma unroll
        for (int t2 = 0; t2 < 4; t2++) {
#pragma unroll
            for (int r = 0; r < 4; r++) {
                float p = __expf(sc[t2][r]);
                unsigned short pt = (unsigned short)(__builtin_bit_cast(unsigned int, p) >> 16);
                lsum[r] += bf2f(pt);
                pw[(quad * 4 + r) * PSTR + t2 * 16 + l15] = pt;
            }
        }

        // O += P V'  (P via wave-private LDS: C->A layout); swizzled V reads
#pragma unroll
        for (int pt = 0; pt < 2; pt++) {
            short8 pa = *(const short8*)(&pw[l15 * PSTR + pt * 32 + quad * 8]);
#pragma unroll
            for (int dt = 0; dt < 4; dt++) {
                int ch = (pt * 4 + quad) ^ (l15 & 7);
                short8 vb = *(const short8*)(&Vtlds[buf][(dt * 16 + l15) * 64 + ch * 8]);
                acc[dt] = mfma16(pa, vb, acc[dt]);
            }
        }
    }

    float rinv[4];
#pragma unroll
    for (int r = 0; r < 4; r++) {
        float rs = lsum[r];
#pragma unroll
        for (int off = 1; off < 16; off <<= 1) rs += __shfl_xor(rs, off);
        rinv[r] = 1.0f / rs;
    }

    int b = bh >> 4, h = bh & 15;
#pragma unroll
    for (int dt = 0; dt < 4; dt++) {
#pragma unroll
        for (int r = 0; r < 4; r++) {
            int q = q0 + quad * 4 + r;
            int d = dt * 16 + l15;
            Ob[((size_t)(b * SEQ + q)) * HIDDEN + h * 64 + d] = f2bf(acc[dt][r] * rinv[r]);
        }
    }
}

// ---------------------------------------------------------------- launch
extern "C" void kernel_launch(void* const* d_in, const int* in_sizes, int n_in,
                              void* d_out, int out_size, void* d_ws, size_t ws_size,
                              hipStream_t stream) {
    const float* x  = (const float*)d_in[0];
    const float* Wq = (const float*)d_in[1];
    const float* Wk = (const float*)d_in[2];
    const float* Wv = (const float*)d_in[3];
    const float* Wo = (const float*)d_in[4];
    const float* qp = (const float*)d_in[5];
    const float* qa = (const float*)d_in[6];
    char* ws = (char*)d_ws;

    unsigned short* Xb  = (unsigned short*)(ws);                      // 8 MB (reused as Ob)
    unsigned short* Wt  = (unsigned short*)(ws + (size_t)( 8 << 20)); // 8 MB (4 x 2MB, q/k/v/o)
    unsigned short* Qp_ = (unsigned short*)(ws + (size_t)(16 << 20)); // 16 MB
    unsigned short* Kp_ = (unsigned short*)(ws + (size_t)(32 << 20)); // 16 MB
    unsigned short* Vnt = (unsigned short*)(ws + (size_t)(48 << 20)); // 8 MB
    unsigned short* Vpt = (unsigned short*)(ws + (size_t)(56 << 20)); // 8 MB
    float* mod  = (float*)(ws + (size_t)(64 << 20));
    float* posc = mod + 1024;
    float* poss = posc + 2048;
    float* out  = (float*)d_out;

    prep_kernel<<<8, 256, 0, stream>>>(qp, qa, mod, posc, poss);
    convert_x_kernel<<<4096, 256, 0, stream>>>(x, Xb);
    transpose_w_kernel<<<dim3(16, 16, 4), 256, 0, stream>>>(Wq, Wk, Wv, Wo, Wt);
    gemm_kernel<<<dim3(32, 8, 3), 256, 0, stream>>>(Xb, Wt, Qp_, Kp_, Vnt, out,
                                                    mod, posc, poss, 0);
    vshift_kernel<<<dim3(32, 32), 256, 0, stream>>>(Vnt, Vpt);
    attn_kernel<<<dim3(32, 32), 256, 0, stream>>>(Qp_, Kp_, Vpt, Xb /*Ob*/);
    gemm_kernel<<<dim3(32, 8, 1), 256, 0, stream>>>(Xb, Wt, Qp_, Kp_, Vnt, out,
                                                    mod, posc, poss, 3);
}

// Round 7
// 292.907 us; speedup vs baseline: 1.4689x; 1.0632x over previous
//
#include <hip/hip_runtime.h>
#include <hip/hip_bf16.h>
#include <math.h>

// Problem constants
#define HIDDEN 1024
#define HEADS  16
#define HDIM   64
#define BATCH  2
#define SEQ    2048
#define ROWS   (BATCH*SEQ)   // 4096
#define BH     (BATCH*HEADS) // 32

typedef __attribute__((ext_vector_type(8))) short  short8;
typedef __attribute__((ext_vector_type(8))) __bf16 bf16x8;
typedef __attribute__((ext_vector_type(4))) float  f32x4;

static __device__ __forceinline__ unsigned short f2bf(float f) {
    unsigned int u = __builtin_bit_cast(unsigned int, f);
    u += 0x7FFFu + ((u >> 16) & 1u);   // round-to-nearest-even
    return (unsigned short)(u >> 16);
}
static __device__ __forceinline__ float bf2f(unsigned short h) {
    unsigned int u = ((unsigned int)h) << 16;
    return __builtin_bit_cast(float, u);
}
static __device__ __forceinline__ f32x4 mfma16(short8 a, short8 b, f32x4 c) {
    return __builtin_amdgcn_mfma_f32_16x16x32_bf16(
        __builtin_bit_cast(bf16x8, a), __builtin_bit_cast(bf16x8, b), c, 0, 0, 0);
}
// async global->LDS, 16B per lane; lds dest = wave-uniform base + lane*16
static __device__ __forceinline__ void gl_lds16(const unsigned short* g, unsigned short* l) {
    __builtin_amdgcn_global_load_lds(
        (const __attribute__((address_space(1))) unsigned int*)g,
        (__attribute__((address_space(3))) unsigned int*)l, 16, 0, 0);
}

// ---------------------------------------------------------------- prep
__global__ void prep_kernel(const float* __restrict__ qp, const float* __restrict__ qa,
                            float* __restrict__ mod, float* __restrict__ posc,
                            float* __restrict__ poss) {
    int i = blockIdx.x * 256 + threadIdx.x;
    if (i < HIDDEN) mod[i] = cosf(qp[i]) * qa[i];
    if (i < SEQ) {
        float ang = (float)i * (6.283185307179586f / (float)SEQ);
        posc[i] = cosf(ang);
        poss[i] = sinf(ang);
    }
}

// ---------------------------------------------------------------- x -> bf16
__global__ void convert_x_kernel(const float* __restrict__ x, unsigned short* __restrict__ xb) {
    int i = (blockIdx.x * 256 + threadIdx.x) * 4;
    float4 v = *(const float4*)(x + i);
    ushort4 o;
    o.x = f2bf(v.x); o.y = f2bf(v.y); o.z = f2bf(v.z); o.w = f2bf(v.w);
    *(ushort4*)(xb + i) = o;
}

// ---------------------------------------------------------------- W -> bf16 transposed  Wt[n][k] = W[k][n]
__global__ __launch_bounds__(256) void transpose_w_kernel(
    const float* __restrict__ w0, const float* __restrict__ w1,
    const float* __restrict__ w2, const float* __restrict__ w3,
    unsigned short* __restrict__ wt) {
    __shared__ unsigned short tile[64][72];
    const float* src = (blockIdx.z == 0) ? w0 : (blockIdx.z == 1) ? w1 : (blockIdx.z == 2) ? w2 : w3;
    unsigned short* dst = wt + (size_t)blockIdx.z * HIDDEN * HIDDEN;
    int n0 = blockIdx.x * 64, k0 = blockIdx.y * 64;
    int t = threadIdx.x;
    int cg = t & 15, r0 = t >> 4;
#pragma unroll
    for (int rr = 0; rr < 4; rr++) {
        int kl = r0 + rr * 16;
        float4 v = *(const float4*)(src + (size_t)(k0 + kl) * HIDDEN + n0 + cg * 4);
        tile[cg*4+0][kl] = f2bf(v.x);
        tile[cg*4+1][kl] = f2bf(v.y);
        tile[cg*4+2][kl] = f2bf(v.z);
        tile[cg*4+3][kl] = f2bf(v.w);
    }
    __syncthreads();
#pragma unroll
    for (int rr = 0; rr < 4; rr++) {
        int nl = r0 + rr * 16;
        ushort4 o;
        o.x = tile[nl][cg*4+0]; o.y = tile[nl][cg*4+1];
        o.z = tile[nl][cg*4+2]; o.w = tile[nl][cg*4+3];
        *(ushort4*)(dst + (size_t)(n0 + nl) * HIDDEN + k0 + cg * 4) = o;
    }
}

// ---------------------------------------------------------------- GEMM (m97 structure + XOR swizzle)
// LDS[r][ci] holds global chunk ci ^ ((r>>1)&3)  (chunk = 8 shorts = 16 B).
// Stage: lane chunk (lane&3), row rbase+(lane>>2) -> source chunk (lane&3)^((lane>>3)&3).
// Read: global chunk `quad` at row base+l15 -> LDS chunk quad^((l15>>1)&3).
// Fragment-read banks: 16*(l15&1) + 4*(quad^((l15>>1)&3)) -> all 32 banks, 2-way = free.
// grid = (mtiles=32, ntiles=8, z): id%8 = mtile%8 -> A-row-tile pinned to one XCD.
__global__ __launch_bounds__(256) void gemm_kernel(
    const unsigned short* __restrict__ A, const unsigned short* __restrict__ WtBase,
    unsigned short* __restrict__ Qp, unsigned short* __restrict__ Kp,
    unsigned short* __restrict__ Vnt, float* __restrict__ Out,
    const float* __restrict__ mod, const float* __restrict__ posc,
    const float* __restrict__ poss, int mode0) {
    __shared__ unsigned short Alds[128 * 32];   // 8KB, unpadded (global_load_lds)
    __shared__ unsigned short Blds[128 * 32];
    const int mode = mode0 + blockIdx.z;
    const unsigned short* Bt = WtBase + (size_t)mode * HIDDEN * HIDDEN;
    const int m0 = blockIdx.x * 128, n0 = blockIdx.y * 128;
    const int tid = threadIdx.x;
    const int wave = tid >> 6, lane = tid & 63, quad = lane >> 4, l15 = lane & 15;
    const int wr = wave >> 1, wc = wave & 1;
    const int srow = lane >> 2;
    const int schunk = (lane & 3) ^ ((lane >> 3) & 3);   // swizzled source chunk
    const int rchunk = quad ^ ((l15 >> 1) & 3);          // swizzled read chunk

    f32x4 acc[4][4];
    const f32x4 z4 = {0.f, 0.f, 0.f, 0.f};
#pragma unroll
    for (int i = 0; i < 4; i++)
#pragma unroll
        for (int j = 0; j < 4; j++) acc[i][j] = z4;

    for (int k0 = 0; k0 < HIDDEN; k0 += 32) {
#pragma unroll
        for (int c = 0; c < 2; c++) {
            int rbase = (wave * 2 + c) * 16;
            gl_lds16(A  + (size_t)(m0 + rbase + srow) * HIDDEN + k0 + schunk * 8,
                     &Alds[rbase * 32]);
            gl_lds16(Bt + (size_t)(n0 + rbase + srow) * HIDDEN + k0 + schunk * 8,
                     &Blds[rbase * 32]);
        }
        __syncthreads();
        short8 aF[4], bF[4];
#pragma unroll
        for (int i = 0; i < 4; i++)
            aF[i] = *(const short8*)(&Alds[(wr * 64 + i * 16 + l15) * 32 + rchunk * 8]);
#pragma unroll
        for (int j = 0; j < 4; j++)
            bF[j] = *(const short8*)(&Blds[(wc * 64 + j * 16 + l15) * 32 + rchunk * 8]);
#pragma unroll
        for (int i = 0; i < 4; i++)
#pragma unroll
            for (int j = 0; j < 4; j++)
                acc[i][j] = mfma16(aF[i], bF[j], acc[i][j]);
        __syncthreads();
    }

#pragma unroll
    for (int i = 0; i < 4; i++) {
        int mbase = m0 + wr * 64 + i * 16 + quad * 4;
#pragma unroll
        for (int j = 0; j < 4; j++) {
            int n = n0 + wc * 64 + j * 16 + l15;
#pragma unroll
            for (int r = 0; r < 4; r++) {
                float val = acc[i][j][r];
                int mm = mbase + r;
                if (mode == 3) {
                    Out[(size_t)mm * HIDDEN + n] = val;
                } else {
                    int b = mm >> 11, ss = mm & 2047;
                    int h = n >> 6, d = n & 63;
                    float vm = val * mod[n];
                    if (mode == 0) {
                        size_t base = ((size_t)(b * HEADS + h) * SEQ + ss) * 128;
                        Qp[base + d]      = f2bf(vm * posc[ss] * 0.125f);
                        Qp[base + 64 + d] = f2bf(vm * poss[ss] * 0.125f);
                    } else if (mode == 1) {
                        size_t base = ((size_t)(b * HEADS + h) * SEQ + ss) * 128;
                        Kp[base + d]      = f2bf(vm * posc[ss]);
                        Kp[base + 64 + d] = f2bf(vm * poss[ss]);
                    } else {
                        Vnt[((size_t)(b * HEADS + h) * SEQ + ss) * 64 + d] = f2bf(vm);
                    }
                }
            }
        }
    }
}

// ---------------------------------------------------------------- V shift + transpose
// grid = (bh=32, stile=32): bh fast -> same XCD as attn's consumer of Vpt[bh]
__global__ __launch_bounds__(256) void vshift_kernel(const unsigned short* __restrict__ Vnt,
                                                     unsigned short* __restrict__ Vpt) {
    __shared__ unsigned short lds[65][72];
    int bh = blockIdx.x, s0 = blockIdx.y * 64;
    int t = threadIdx.x;
    int cg = t & 15, r0 = t >> 4;
#pragma unroll
    for (int rr = 0; rr < 4; rr++) {
        int row = r0 + rr * 16;
        ushort4 v = *(const ushort4*)(Vnt + ((size_t)bh * SEQ + s0 + row) * 64 + cg * 4);
        *(ushort4*)(&lds[row][cg * 4]) = v;
    }
    if (t < 16) {
        int srow = (s0 + 64) & (SEQ - 1);
        ushort4 v = *(const ushort4*)(Vnt + ((size_t)bh * SEQ + srow) * 64 + t * 4);
        *(ushort4*)(&lds[64][t * 4]) = v;
    }
    __syncthreads();
    int d = t & 63, sb = (t >> 6) * 16;
    unsigned short outv[16];
#pragma unroll
    for (int k = 0; k < 16; k++) {
        float a = bf2f(lds[sb + k][d]), b = bf2f(lds[sb + k + 1][d]);
        outv[k] = f2bf((a + b) * 0.7071067811865476f);
    }
    unsigned short* dst = Vpt + ((size_t)bh * 64 + d) * SEQ + s0 + sb;
#pragma unroll
    for (int k = 0; k < 16; k += 4) {
        ushort4 o; o.x = outv[k]; o.y = outv[k+1]; o.z = outv[k+2]; o.w = outv[k+3];
        *(ushort4*)(dst + k) = o;
    }
}

// ---------------------------------------------------------------- flash attention
// 32 q-rows per wave (128 per block): K/V LDS fragment reads amortized over 2x MFMA.
// Double-buffered async K/V staging (global_load_lds, one barrier/tile), XOR-swizzled.
// grid = (bh=32, qtile=16) = 512 blocks = exactly 2/CU; bh fast -> per-XCD K/V L2 residency.
#define KT 64
#define PSTR 76    // P row stride: quad bank offsets {0,24,16,8} -> <=2-way
__global__ __launch_bounds__(256) void attn_kernel(const unsigned short* __restrict__ Qp,
                                                   const unsigned short* __restrict__ Kp,
                                                   const unsigned short* __restrict__ Vpt,
                                                   unsigned short* __restrict__ Ob) {
    __shared__ unsigned short Klds[2][KT * 128];     // 2 x 16 KB, unpadded
    __shared__ unsigned short Vtlds[2][64 * 64];     // 2 x 8 KB, unpadded
    __shared__ unsigned short Plds[4 * 32 * PSTR];   // 19456 B
    const int bh = blockIdx.x;
    const int tid = threadIdx.x, wave = tid >> 6, lane = tid & 63;
    const int quad = lane >> 4, l15 = lane & 15;
    const int q0 = blockIdx.y * 128 + wave * 32;

    short8 qf[2][4];
#pragma unroll
    for (int g = 0; g < 2; g++) {
        const unsigned short* Qbase = Qp + ((size_t)bh * SEQ + q0 + g * 16 + l15) * 128;
#pragma unroll
        for (int kk = 0; kk < 4; kk++)
            qf[g][kk] = *(const short8*)(Qbase + kk * 32 + quad * 8);
    }

    const f32x4 z4 = {0.f, 0.f, 0.f, 0.f};
    f32x4 acc[2][4];
#pragma unroll
    for (int g = 0; g < 2; g++)
#pragma unroll
        for (int dt = 0; dt < 4; dt++) acc[g][dt] = z4;
    float lsum[2][4];
#pragma unroll
    for (int g = 0; g < 2; g++)
#pragma unroll
        for (int r = 0; r < 4; r++) lsum[g][r] = 0.f;

    unsigned short* pw = &Plds[wave * 32 * PSTR];

    const unsigned short* Kbh = Kp  + (size_t)bh * SEQ * 128;
    const unsigned short* Vbh = Vpt + (size_t)bh * 64 * SEQ;

    // stage tile at key offset j into buffer buf (async; lands by next barrier)
    auto stage = [&](int j, int buf) {
#pragma unroll
        for (int p = 0; p < 4; p++) {               // K: 4 passes of 16 rows
            int rb = p * 16 + wave * 4;             // wave-uniform base row
            int r  = rb + (lane >> 4);
            int c  = (lane & 15) ^ (r & 15);        // swizzled source chunk
            gl_lds16(Kbh + (size_t)(j + r) * 128 + c * 8, &Klds[buf][rb * 128]);
        }
#pragma unroll
        for (int p = 0; p < 2; p++) {               // V^T: 2 passes of 32 d-rows
            int rb = p * 32 + wave * 8;
            int r  = rb + (lane >> 3);
            int c  = (lane & 7) ^ (r & 7);
            gl_lds16(Vbh + (size_t)r * SEQ + j + c * 8, &Vtlds[buf][rb * 64]);
        }
    };

    stage(0, 0);
    for (int it = 0; it < SEQ / KT; it++) {
        __syncthreads();                 // drains tile `it` loads; prev buf reads done
        if (it + 1 < SEQ / KT) stage((it + 1) * KT, (it + 1) & 1);   // overlap w/ compute
        const int buf = it & 1;

        // S = Q K^T over 64 keys x 32 q-rows; swizzled K reads (conflict-free)
#pragma unroll
        for (int g = 0; g < 2; g++) {
#pragma unroll
            for (int t2 = 0; t2 < 4; t2++) {
                f32x4 sc = z4;
#pragma unroll
                for (int kk = 0; kk < 4; kk++) {
                    int ch = (kk * 4 + quad) ^ l15;
                    short8 kf = *(const short8*)(&Klds[buf][(t2 * 16 + l15) * 128 + ch * 8]);
                    sc = mfma16(qf[g][kk], kf, sc);
                }
                // P = exp(S), truncation-packed to bf16; lsum accumulates the PACKED
                // value so the truncation bias cancels in the num/den ratio.
#pragma unroll
                for (int r = 0; r < 4; r++) {
                    float p = __expf(sc[r]);
                    unsigned short pt = (unsigned short)(__builtin_bit_cast(unsigned int, p) >> 16);
                    lsum[g][r] += bf2f(pt);
                    pw[(g * 16 + quad * 4 + r) * PSTR + t2 * 16 + l15] = pt;
                }
            }
        }

        // O += P V'  (P via wave-private LDS: C->A layout); swizzled V reads
#pragma unroll
        for (int g = 0; g < 2; g++) {
#pragma unroll
            for (int pt = 0; pt < 2; pt++) {
                short8 pa = *(const short8*)(&pw[(g * 16 + l15) * PSTR + pt * 32 + quad * 8]);
#pragma unroll
                for (int dt = 0; dt < 4; dt++) {
                    int ch = (pt * 4 + quad) ^ (l15 & 7);
                    short8 vb = *(const short8*)(&Vtlds[buf][(dt * 16 + l15) * 64 + ch * 8]);
                    acc[g][dt] = mfma16(pa, vb, acc[g][dt]);
                }
            }
        }
    }

    int b = bh >> 4, h = bh & 15;
#pragma unroll
    for (int g = 0; g < 2; g++) {
        float rinv[4];
#pragma unroll
        for (int r = 0; r < 4; r++) {
            float rs = lsum[g][r];
#pragma unroll
            for (int off = 1; off < 16; off <<= 1) rs += __shfl_xor(rs, off);
            rinv[r] = 1.0f / rs;
        }
#pragma unroll
        for (int dt = 0; dt < 4; dt++) {
#pragma unroll
            for (int r = 0; r < 4; r++) {
                int q = q0 + g * 16 + quad * 4 + r;
                int d = dt * 16 + l15;
                Ob[((size_t)(b * SEQ + q)) * HIDDEN + h * 64 + d] = f2bf(acc[g][dt][r] * rinv[r]);
            }
        }
    }
}

// ---------------------------------------------------------------- launch
extern "C" void kernel_launch(void* const* d_in, const int* in_sizes, int n_in,
                              void* d_out, int out_size, void* d_ws, size_t ws_size,
                              hipStream_t stream) {
    const float* x  = (const float*)d_in[0];
    const float* Wq = (const float*)d_in[1];
    const float* Wk = (const float*)d_in[2];
    const float* Wv = (const float*)d_in[3];
    const float* Wo = (const float*)d_in[4];
    const float* qp = (const float*)d_in[5];
    const float* qa = (const float*)d_in[6];
    char* ws = (char*)d_ws;

    unsigned short* Xb  = (unsigned short*)(ws);                      // 8 MB (reused as Ob)
    unsigned short* Wt  = (unsigned short*)(ws + (size_t)( 8 << 20)); // 8 MB (4 x 2MB, q/k/v/o)
    unsigned short* Qp_ = (unsigned short*)(ws + (size_t)(16 << 20)); // 16 MB
    unsigned short* Kp_ = (unsigned short*)(ws + (size_t)(32 << 20)); // 16 MB
    unsigned short* Vnt = (unsigned short*)(ws + (size_t)(48 << 20)); // 8 MB
    unsigned short* Vpt = (unsigned short*)(ws + (size_t)(56 << 20)); // 8 MB
    float* mod  = (float*)(ws + (size_t)(64 << 20));
    float* posc = mod + 1024;
    float* poss = posc + 2048;
    float* out  = (float*)d_out;

    prep_kernel<<<8, 256, 0, stream>>>(qp, qa, mod, posc, poss);
    convert_x_kernel<<<4096, 256, 0, stream>>>(x, Xb);
    transpose_w_kernel<<<dim3(16, 16, 4), 256, 0, stream>>>(Wq, Wk, Wv, Wo, Wt);
    gemm_kernel<<<dim3(32, 8, 3), 256, 0, stream>>>(Xb, Wt, Qp_, Kp_, Vnt, out,
                                                    mod, posc, poss, 0);
    vshift_kernel<<<dim3(32, 32), 256, 0, stream>>>(Vnt, Vpt);
    attn_kernel<<<dim3(32, 16), 256, 0, stream>>>(Qp_, Kp_, Vpt, Xb /*Ob*/);
    gemm_kernel<<<dim3(32, 8, 1), 256, 0, stream>>>(Xb, Wt, Qp_, Kp_, Vnt, out,
                                                    mod, posc, poss, 3);
}

// Round 8
// 285.995 us; speedup vs baseline: 1.5044x; 1.0242x over previous
//
#include <hip/hip_runtime.h>
#include <hip/hip_bf16.h>
#include <math.h>

// Problem constants
#define HIDDEN 1024
#define HEADS  16
#define HDIM   64
#define BATCH  2
#define SEQ    2048
#define ROWS   (BATCH*SEQ)   // 4096
#define BH     (BATCH*HEADS) // 32

typedef __attribute__((ext_vector_type(8))) short  short8;
typedef __attribute__((ext_vector_type(8))) __bf16 bf16x8;
typedef __attribute__((ext_vector_type(4))) float  f32x4;

static __device__ __forceinline__ unsigned short f2bf(float f) {
    unsigned int u = __builtin_bit_cast(unsigned int, f);
    u += 0x7FFFu + ((u >> 16) & 1u);   // round-to-nearest-even
    return (unsigned short)(u >> 16);
}
static __device__ __forceinline__ float bf2f(unsigned short h) {
    unsigned int u = ((unsigned int)h) << 16;
    return __builtin_bit_cast(float, u);
}
static __device__ __forceinline__ f32x4 mfma16(short8 a, short8 b, f32x4 c) {
    return __builtin_amdgcn_mfma_f32_16x16x32_bf16(
        __builtin_bit_cast(bf16x8, a), __builtin_bit_cast(bf16x8, b), c, 0, 0, 0);
}
// async global->LDS, 16B per lane; lds dest = wave-uniform base + lane*16
static __device__ __forceinline__ void gl_lds16(const unsigned short* g, unsigned short* l) {
    __builtin_amdgcn_global_load_lds(
        (const __attribute__((address_space(1))) unsigned int*)g,
        (__attribute__((address_space(3))) unsigned int*)l, 16, 0, 0);
}

// ---------------------------------------------------------------- prep
__global__ void prep_kernel(const float* __restrict__ qp, const float* __restrict__ qa,
                            float* __restrict__ mod, float* __restrict__ posc,
                            float* __restrict__ poss) {
    int i = blockIdx.x * 256 + threadIdx.x;
    if (i < HIDDEN) mod[i] = cosf(qp[i]) * qa[i];
    if (i < SEQ) {
        float ang = (float)i * (6.283185307179586f / (float)SEQ);
        posc[i] = cosf(ang);
        poss[i] = sinf(ang);
    }
}

// ---------------------------------------------------------------- x -> bf16
__global__ void convert_x_kernel(const float* __restrict__ x, unsigned short* __restrict__ xb) {
    int i = (blockIdx.x * 256 + threadIdx.x) * 4;
    float4 v = *(const float4*)(x + i);
    ushort4 o;
    o.x = f2bf(v.x); o.y = f2bf(v.y); o.z = f2bf(v.z); o.w = f2bf(v.w);
    *(ushort4*)(xb + i) = o;
}

// ---------------------------------------------------------------- W -> bf16 transposed  Wt[n][k] = W[k][n]
__global__ __launch_bounds__(256) void transpose_w_kernel(
    const float* __restrict__ w0, const float* __restrict__ w1,
    const float* __restrict__ w2, const float* __restrict__ w3,
    unsigned short* __restrict__ wt) {
    __shared__ unsigned short tile[64][72];
    const float* src = (blockIdx.z == 0) ? w0 : (blockIdx.z == 1) ? w1 : (blockIdx.z == 2) ? w2 : w3;
    unsigned short* dst = wt + (size_t)blockIdx.z * HIDDEN * HIDDEN;
    int n0 = blockIdx.x * 64, k0 = blockIdx.y * 64;
    int t = threadIdx.x;
    int cg = t & 15, r0 = t >> 4;
#pragma unroll
    for (int rr = 0; rr < 4; rr++) {
        int kl = r0 + rr * 16;
        float4 v = *(const float4*)(src + (size_t)(k0 + kl) * HIDDEN + n0 + cg * 4);
        tile[cg*4+0][kl] = f2bf(v.x);
        tile[cg*4+1][kl] = f2bf(v.y);
        tile[cg*4+2][kl] = f2bf(v.z);
        tile[cg*4+3][kl] = f2bf(v.w);
    }
    __syncthreads();
#pragma unroll
    for (int rr = 0; rr < 4; rr++) {
        int nl = r0 + rr * 16;
        ushort4 o;
        o.x = tile[nl][cg*4+0]; o.y = tile[nl][cg*4+1];
        o.z = tile[nl][cg*4+2]; o.w = tile[nl][cg*4+3];
        *(ushort4*)(dst + (size_t)(n0 + nl) * HIDDEN + k0 + cg * 4) = o;
    }
}

// ---------------------------------------------------------------- GEMM (m97 structure + XOR swizzle)
// grid = (mtiles=32, ntiles=8, z): id%8 = mtile%8 -> A-row-tile pinned to one XCD.
__global__ __launch_bounds__(256) void gemm_kernel(
    const unsigned short* __restrict__ A, const unsigned short* __restrict__ WtBase,
    unsigned short* __restrict__ Qp, unsigned short* __restrict__ Kp,
    unsigned short* __restrict__ Vnt, float* __restrict__ Out,
    const float* __restrict__ mod, const float* __restrict__ posc,
    const float* __restrict__ poss, int mode0) {
    __shared__ unsigned short Alds[128 * 32];   // 8KB, unpadded (global_load_lds)
    __shared__ unsigned short Blds[128 * 32];
    const int mode = mode0 + blockIdx.z;
    const unsigned short* Bt = WtBase + (size_t)mode * HIDDEN * HIDDEN;
    const int m0 = blockIdx.x * 128, n0 = blockIdx.y * 128;
    const int tid = threadIdx.x;
    const int wave = tid >> 6, lane = tid & 63, quad = lane >> 4, l15 = lane & 15;
    const int wr = wave >> 1, wc = wave & 1;
    const int srow = lane >> 2;
    const int schunk = (lane & 3) ^ ((lane >> 3) & 3);   // swizzled source chunk
    const int rchunk = quad ^ ((l15 >> 1) & 3);          // swizzled read chunk

    f32x4 acc[4][4];
    const f32x4 z4 = {0.f, 0.f, 0.f, 0.f};
#pragma unroll
    for (int i = 0; i < 4; i++)
#pragma unroll
        for (int j = 0; j < 4; j++) acc[i][j] = z4;

    for (int k0 = 0; k0 < HIDDEN; k0 += 32) {
#pragma unroll
        for (int c = 0; c < 2; c++) {
            int rbase = (wave * 2 + c) * 16;
            gl_lds16(A  + (size_t)(m0 + rbase + srow) * HIDDEN + k0 + schunk * 8,
                     &Alds[rbase * 32]);
            gl_lds16(Bt + (size_t)(n0 + rbase + srow) * HIDDEN + k0 + schunk * 8,
                     &Blds[rbase * 32]);
        }
        __syncthreads();
        short8 aF[4], bF[4];
#pragma unroll
        for (int i = 0; i < 4; i++)
            aF[i] = *(const short8*)(&Alds[(wr * 64 + i * 16 + l15) * 32 + rchunk * 8]);
#pragma unroll
        for (int j = 0; j < 4; j++)
            bF[j] = *(const short8*)(&Blds[(wc * 64 + j * 16 + l15) * 32 + rchunk * 8]);
#pragma unroll
        for (int i = 0; i < 4; i++)
#pragma unroll
            for (int j = 0; j < 4; j++)
                acc[i][j] = mfma16(aF[i], bF[j], acc[i][j]);
        __syncthreads();
    }

#pragma unroll
    for (int i = 0; i < 4; i++) {
        int mbase = m0 + wr * 64 + i * 16 + quad * 4;
#pragma unroll
        for (int j = 0; j < 4; j++) {
            int n = n0 + wc * 64 + j * 16 + l15;
#pragma unroll
            for (int r = 0; r < 4; r++) {
                float val = acc[i][j][r];
                int mm = mbase + r;
                if (mode == 3) {
                    Out[(size_t)mm * HIDDEN + n] = val;
                } else {
                    int b = mm >> 11, ss = mm & 2047;
                    int h = n >> 6, d = n & 63;
                    float vm = val * mod[n];
                    if (mode == 0) {
                        // 0.125 * log2(e): exp(s) computed as exp2 in attn
                        size_t base = ((size_t)(b * HEADS + h) * SEQ + ss) * 128;
                        Qp[base + d]      = f2bf(vm * posc[ss] * 0.18033688011112042f);
                        Qp[base + 64 + d] = f2bf(vm * poss[ss] * 0.18033688011112042f);
                    } else if (mode == 1) {
                        size_t base = ((size_t)(b * HEADS + h) * SEQ + ss) * 128;
                        Kp[base + d]      = f2bf(vm * posc[ss]);
                        Kp[base + 64 + d] = f2bf(vm * poss[ss]);
                    } else {
                        Vnt[((size_t)(b * HEADS + h) * SEQ + ss) * 64 + d] = f2bf(vm);
                    }
                }
            }
        }
    }
}

// ---------------------------------------------------------------- V shift + transpose
// grid = (bh=32, stile=32): bh fast -> same XCD as attn's consumer of Vpt[bh]
__global__ __launch_bounds__(256) void vshift_kernel(const unsigned short* __restrict__ Vnt,
                                                     unsigned short* __restrict__ Vpt) {
    __shared__ unsigned short lds[65][72];
    int bh = blockIdx.x, s0 = blockIdx.y * 64;
    int t = threadIdx.x;
    int cg = t & 15, r0 = t >> 4;
#pragma unroll
    for (int rr = 0; rr < 4; rr++) {
        int row = r0 + rr * 16;
        ushort4 v = *(const ushort4*)(Vnt + ((size_t)bh * SEQ + s0 + row) * 64 + cg * 4);
        *(ushort4*)(&lds[row][cg * 4]) = v;
    }
    if (t < 16) {
        int srow = (s0 + 64) & (SEQ - 1);
        ushort4 v = *(const ushort4*)(Vnt + ((size_t)bh * SEQ + srow) * 64 + t * 4);
        *(ushort4*)(&lds[64][t * 4]) = v;
    }
    __syncthreads();
    int d = t & 63, sb = (t >> 6) * 16;
    unsigned short outv[16];
#pragma unroll
    for (int k = 0; k < 16; k++) {
        float a = bf2f(lds[sb + k][d]), b = bf2f(lds[sb + k + 1][d]);
        outv[k] = f2bf((a + b) * 0.7071067811865476f);
    }
    unsigned short* dst = Vpt + ((size_t)bh * 64 + d) * SEQ + s0 + sb;
#pragma unroll
    for (int k = 0; k < 16; k += 4) {
        ushort4 o; o.x = outv[k]; o.y = outv[k+1]; o.z = outv[k+2]; o.w = outv[k+3];
        *(ushort4*)(dst + k) = o;
    }
}

// ---------------------------------------------------------------- flash attention
// 32 q-rows per wave; K/V fragment reads hoisted out of the q-group loop (shared across
// both 16-row groups -> K LDS reads halved, V halved). exp2-based softmax (log2e folded
// into Q scale). Double-buffered async K/V staging, XOR-swizzled, one barrier per tile.
// grid = (bh=32, qtile=16) = 512 blocks = 2/CU; bh fast -> per-XCD K/V L2 residency.
#define KT 64
#define PSTR 76    // P row stride: quad bank offsets {0,24,16,8} -> <=2-way
__global__ __launch_bounds__(256) void attn_kernel(const unsigned short* __restrict__ Qp,
                                                   const unsigned short* __restrict__ Kp,
                                                   const unsigned short* __restrict__ Vpt,
                                                   unsigned short* __restrict__ Ob) {
    __shared__ unsigned short Klds[2][KT * 128];     // 2 x 16 KB, unpadded
    __shared__ unsigned short Vtlds[2][64 * 64];     // 2 x 8 KB, unpadded
    __shared__ unsigned short Plds[4 * 32 * PSTR];   // 19456 B
    const int bh = blockIdx.x;
    const int tid = threadIdx.x, wave = tid >> 6, lane = tid & 63;
    const int quad = lane >> 4, l15 = lane & 15;
    const int q0 = blockIdx.y * 128 + wave * 32;

    short8 qf[2][4];
#pragma unroll
    for (int g = 0; g < 2; g++) {
        const unsigned short* Qbase = Qp + ((size_t)bh * SEQ + q0 + g * 16 + l15) * 128;
#pragma unroll
        for (int kk = 0; kk < 4; kk++)
            qf[g][kk] = *(const short8*)(Qbase + kk * 32 + quad * 8);
    }

    const f32x4 z4 = {0.f, 0.f, 0.f, 0.f};
    f32x4 acc[2][4];
#pragma unroll
    for (int g = 0; g < 2; g++)
#pragma unroll
        for (int dt = 0; dt < 4; dt++) acc[g][dt] = z4;
    float lsum[2][4];
#pragma unroll
    for (int g = 0; g < 2; g++)
#pragma unroll
        for (int r = 0; r < 4; r++) lsum[g][r] = 0.f;

    unsigned short* pw = &Plds[wave * 32 * PSTR];

    const unsigned short* Kbh = Kp  + (size_t)bh * SEQ * 128;
    const unsigned short* Vbh = Vpt + (size_t)bh * 64 * SEQ;

    // stage tile at key offset j into buffer buf (async; lands by next barrier)
    auto stage = [&](int j, int buf) {
#pragma unroll
        for (int p = 0; p < 4; p++) {               // K: 4 passes of 16 rows
            int rb = p * 16 + wave * 4;             // wave-uniform base row
            int r  = rb + (lane >> 4);
            int c  = (lane & 15) ^ (r & 15);        // swizzled source chunk
            gl_lds16(Kbh + (size_t)(j + r) * 128 + c * 8, &Klds[buf][rb * 128]);
        }
#pragma unroll
        for (int p = 0; p < 2; p++) {               // V^T: 2 passes of 32 d-rows
            int rb = p * 32 + wave * 8;
            int r  = rb + (lane >> 3);
            int c  = (lane & 7) ^ (r & 7);
            gl_lds16(Vbh + (size_t)r * SEQ + j + c * 8, &Vtlds[buf][rb * 64]);
        }
    };

    stage(0, 0);
    for (int it = 0; it < SEQ / KT; it++) {
        __syncthreads();                 // drains tile `it` loads; prev buf reads done
        if (it + 1 < SEQ / KT) stage((it + 1) * KT, (it + 1) & 1);   // overlap w/ compute
        const int buf = it & 1;

        // S = Q K^T over 64 keys x 32 q-rows; kf shared across both q-groups
#pragma unroll
        for (int t2 = 0; t2 < 4; t2++) {
            f32x4 sc[2] = {z4, z4};
#pragma unroll
            for (int kk = 0; kk < 4; kk++) {
                int ch = (kk * 4 + quad) ^ l15;
                short8 kf = *(const short8*)(&Klds[buf][(t2 * 16 + l15) * 128 + ch * 8]);
#pragma unroll
                for (int g = 0; g < 2; g++)
                    sc[g] = mfma16(qf[g][kk], kf, sc[g]);
            }
            // P = exp2(S) (log2e pre-folded), truncation-packed to bf16; lsum
            // accumulates the PACKED value so the pack bias cancels in num/den.
#pragma unroll
            for (int g = 0; g < 2; g++) {
#pragma unroll
                for (int r = 0; r < 4; r++) {
                    float p = __builtin_amdgcn_exp2f(sc[g][r]);
                    unsigned short pt = (unsigned short)(__builtin_bit_cast(unsigned int, p) >> 16);
                    lsum[g][r] += bf2f(pt);
                    pw[(g * 16 + quad * 4 + r) * PSTR + t2 * 16 + l15] = pt;
                }
            }
        }

        // O += P V'  (P via wave-private LDS: C->A layout); vb shared across q-groups
#pragma unroll
        for (int pt = 0; pt < 2; pt++) {
            short8 pa0 = *(const short8*)(&pw[(l15) * PSTR + pt * 32 + quad * 8]);
            short8 pa1 = *(const short8*)(&pw[(16 + l15) * PSTR + pt * 32 + quad * 8]);
#pragma unroll
            for (int dt = 0; dt < 4; dt++) {
                int ch = (pt * 4 + quad) ^ (l15 & 7);
                short8 vb = *(const short8*)(&Vtlds[buf][(dt * 16 + l15) * 64 + ch * 8]);
                acc[0][dt] = mfma16(pa0, vb, acc[0][dt]);
                acc[1][dt] = mfma16(pa1, vb, acc[1][dt]);
            }
        }
    }

    int b = bh >> 4, h = bh & 15;
#pragma unroll
    for (int g = 0; g < 2; g++) {
        float rinv[4];
#pragma unroll
        for (int r = 0; r < 4; r++) {
            float rs = lsum[g][r];
#pragma unroll
            for (int off = 1; off < 16; off <<= 1) rs += __shfl_xor(rs, off);
            rinv[r] = 1.0f / rs;
        }
#pragma unroll
        for (int dt = 0; dt < 4; dt++) {
#pragma unroll
            for (int r = 0; r < 4; r++) {
                int q = q0 + g * 16 + quad * 4 + r;
                int d = dt * 16 + l15;
                Ob[((size_t)(b * SEQ + q)) * HIDDEN + h * 64 + d] = f2bf(acc[g][dt][r] * rinv[r]);
            }
        }
    }
}

// ---------------------------------------------------------------- launch
extern "C" void kernel_launch(void* const* d_in, const int* in_sizes, int n_in,
                              void* d_out, int out_size, void* d_ws, size_t ws_size,
                              hipStream_t stream) {
    const float* x  = (const float*)d_in[0];
    const float* Wq = (const float*)d_in[1];
    const float* Wk = (const float*)d_in[2];
    const float* Wv = (const float*)d_in[3];
    const float* Wo = (const float*)d_in[4];
    const float* qp = (const float*)d_in[5];
    const float* qa = (const float*)d_in[6];
    char* ws = (char*)d_ws;

    unsigned short* Xb  = (unsigned short*)(ws);                      // 8 MB (reused as Ob)
    unsigned short* Wt  = (unsigned short*)(ws + (size_t)( 8 << 20)); // 8 MB (4 x 2MB, q/k/v/o)
    unsigned short* Qp_ = (unsigned short*)(ws + (size_t)(16 << 20)); // 16 MB
    unsigned short* Kp_ = (unsigned short*)(ws + (size_t)(32 << 20)); // 16 MB
    unsigned short* Vnt = (unsigned short*)(ws + (size_t)(48 << 20)); // 8 MB
    unsigned short* Vpt = (unsigned short*)(ws + (size_t)(56 << 20)); // 8 MB
    float* mod  = (float*)(ws + (size_t)(64 << 20));
    float* posc = mod + 1024;
    float* poss = posc + 2048;
    float* out  = (float*)d_out;

    prep_kernel<<<8, 256, 0, stream>>>(qp, qa, mod, posc, poss);
    convert_x_kernel<<<4096, 256, 0, stream>>>(x, Xb);
    transpose_w_kernel<<<dim3(16, 16, 4), 256, 0, stream>>>(Wq, Wk, Wv, Wo, Wt);
    gemm_kernel<<<dim3(32, 8, 3), 256, 0, stream>>>(Xb, Wt, Qp_, Kp_, Vnt, out,
                                                    mod, posc, poss, 0);
    vshift_kernel<<<dim3(32, 32), 256, 0, stream>>>(Vnt, Vpt);
    attn_kernel<<<dim3(32, 16), 256, 0, stream>>>(Qp_, Kp_, Vpt, Xb /*Ob*/);
    gemm_kernel<<<dim3(32, 8, 1), 256, 0, stream>>>(Xb, Wt, Qp_, Kp_, Vnt, out,
                                                    mod, posc, poss, 3);
}

// Round 9
// 275.348 us; speedup vs baseline: 1.5626x; 1.0387x over previous
//
#include <hip/hip_runtime.h>
#include <hip/hip_bf16.h>
#include <math.h>

// Problem constants
#define HIDDEN 1024
#define HEADS  16
#define HDIM   64
#define BATCH  2
#define SEQ    2048
#define ROWS   (BATCH*SEQ)   // 4096
#define BH     (BATCH*HEADS) // 32

typedef __attribute__((ext_vector_type(8))) short  short8;
typedef __attribute__((ext_vector_type(8))) __bf16 bf16x8;
typedef __attribute__((ext_vector_type(4))) float  f32x4;

static __device__ __forceinline__ unsigned short f2bf(float f) {
    unsigned int u = __builtin_bit_cast(unsigned int, f);
    u += 0x7FFFu + ((u >> 16) & 1u);   // round-to-nearest-even
    return (unsigned short)(u >> 16);
}
static __device__ __forceinline__ float bf2f(unsigned short h) {
    unsigned int u = ((unsigned int)h) << 16;
    return __builtin_bit_cast(float, u);
}
static __device__ __forceinline__ f32x4 mfma16(short8 a, short8 b, f32x4 c) {
    return __builtin_amdgcn_mfma_f32_16x16x32_bf16(
        __builtin_bit_cast(bf16x8, a), __builtin_bit_cast(bf16x8, b), c, 0, 0, 0);
}
// async global->LDS, 16B per lane; lds dest = wave-uniform base + lane*16
static __device__ __forceinline__ void gl_lds16(const unsigned short* g, unsigned short* l) {
    __builtin_amdgcn_global_load_lds(
        (const __attribute__((address_space(1))) unsigned int*)g,
        (__attribute__((address_space(3))) unsigned int*)l, 16, 0, 0);
}

// ---------------------------------------------------------------- x -> bf16 (+ prep folded in)
__global__ void convert_x_kernel(const float* __restrict__ x, unsigned short* __restrict__ xb,
                                 const float* __restrict__ qp, const float* __restrict__ qa,
                                 float* __restrict__ mod, float* __restrict__ posc,
                                 float* __restrict__ poss) {
    int i = (blockIdx.x * 256 + threadIdx.x) * 4;
    float4 v = *(const float4*)(x + i);
    ushort4 o;
    o.x = f2bf(v.x); o.y = f2bf(v.y); o.z = f2bf(v.z); o.w = f2bf(v.w);
    *(ushort4*)(xb + i) = o;
    if (blockIdx.x < 8) {
        int k = blockIdx.x * 256 + threadIdx.x;
        if (k < HIDDEN) mod[k] = cosf(qp[k]) * qa[k];
        if (k < SEQ) {
            float ang = (float)k * (6.283185307179586f / (float)SEQ);
            posc[k] = cosf(ang);
            poss[k] = sinf(ang);
        }
    }
}

// ---------------------------------------------------------------- W -> bf16 transposed  Wt[n][k] = W[k][n]
__global__ __launch_bounds__(256) void transpose_w_kernel(
    const float* __restrict__ w0, const float* __restrict__ w1,
    const float* __restrict__ w2, const float* __restrict__ w3,
    unsigned short* __restrict__ wt) {
    __shared__ unsigned short tile[64][72];
    const float* src = (blockIdx.z == 0) ? w0 : (blockIdx.z == 1) ? w1 : (blockIdx.z == 2) ? w2 : w3;
    unsigned short* dst = wt + (size_t)blockIdx.z * HIDDEN * HIDDEN;
    int n0 = blockIdx.x * 64, k0 = blockIdx.y * 64;
    int t = threadIdx.x;
    int cg = t & 15, r0 = t >> 4;
#pragma unroll
    for (int rr = 0; rr < 4; rr++) {
        int kl = r0 + rr * 16;
        float4 v = *(const float4*)(src + (size_t)(k0 + kl) * HIDDEN + n0 + cg * 4);
        tile[cg*4+0][kl] = f2bf(v.x);
        tile[cg*4+1][kl] = f2bf(v.y);
        tile[cg*4+2][kl] = f2bf(v.z);
        tile[cg*4+3][kl] = f2bf(v.w);
    }
    __syncthreads();
#pragma unroll
    for (int rr = 0; rr < 4; rr++) {
        int nl = r0 + rr * 16;
        ushort4 o;
        o.x = tile[nl][cg*4+0]; o.y = tile[nl][cg*4+1];
        o.z = tile[nl][cg*4+2]; o.w = tile[nl][cg*4+3];
        *(ushort4*)(dst + (size_t)(n0 + nl) * HIDDEN + k0 + cg * 4) = o;
    }
}

// ---------------------------------------------------------------- GEMM (BK=64: 32 MFMA per barrier-pair, 16 K-iters)
// LDS rows 64 shorts = 8 chunks of 16B; XOR swizzle: LDS[r][ci] = g[r][ci ^ (r&7)].
// Stage: lane chunk (lane&7), rows rb+(lane>>3). Read: chunk (h*4+quad)^(l15&7) -> balanced banks.
// grid = (mtiles=32, ntiles=8, z): id%8 = mtile%8 -> A-row-tile pinned to one XCD.
__global__ __launch_bounds__(256) void gemm_kernel(
    const unsigned short* __restrict__ A, const unsigned short* __restrict__ WtBase,
    unsigned short* __restrict__ Qp, unsigned short* __restrict__ Kp,
    unsigned short* __restrict__ Vnt, float* __restrict__ Out,
    const float* __restrict__ mod, const float* __restrict__ posc,
    const float* __restrict__ poss, int mode0) {
    __shared__ unsigned short Alds[128 * 64];   // 16 KB
    __shared__ unsigned short Blds[128 * 64];   // 16 KB
    const int mode = mode0 + blockIdx.z;
    const unsigned short* Bt = WtBase + (size_t)mode * HIDDEN * HIDDEN;
    const int m0 = blockIdx.x * 128, n0 = blockIdx.y * 128;
    const int tid = threadIdx.x;
    const int wave = tid >> 6, lane = tid & 63, quad = lane >> 4, l15 = lane & 15;
    const int wr = wave >> 1, wc = wave & 1;
    const int srow = lane >> 3;
    const int schunk = (lane & 7) ^ (srow & 7);          // swizzled source chunk

    f32x4 acc[4][4];
    const f32x4 z4 = {0.f, 0.f, 0.f, 0.f};
#pragma unroll
    for (int i = 0; i < 4; i++)
#pragma unroll
        for (int j = 0; j < 4; j++) acc[i][j] = z4;

    for (int k0 = 0; k0 < HIDDEN; k0 += 64) {
#pragma unroll
        for (int p = 0; p < 4; p++) {
            int rbase = p * 32 + wave * 8;
            gl_lds16(A  + (size_t)(m0 + rbase + srow) * HIDDEN + k0 + schunk * 8,
                     &Alds[rbase * 64]);
            gl_lds16(Bt + (size_t)(n0 + rbase + srow) * HIDDEN + k0 + schunk * 8,
                     &Blds[rbase * 64]);
        }
        __syncthreads();
        short8 aF[4][2], bF[4][2];
#pragma unroll
        for (int h = 0; h < 2; h++) {
#pragma unroll
            for (int i = 0; i < 4; i++) {
                int row = wr * 64 + i * 16 + l15;
                aF[i][h] = *(const short8*)(&Alds[row * 64 + ((h * 4 + quad) ^ (l15 & 7)) * 8]);
            }
#pragma unroll
            for (int j = 0; j < 4; j++) {
                int row = wc * 64 + j * 16 + l15;
                bF[j][h] = *(const short8*)(&Blds[row * 64 + ((h * 4 + quad) ^ (l15 & 7)) * 8]);
            }
        }
#pragma unroll
        for (int h = 0; h < 2; h++)
#pragma unroll
            for (int i = 0; i < 4; i++)
#pragma unroll
                for (int j = 0; j < 4; j++)
                    acc[i][j] = mfma16(aF[i][h], bF[j][h], acc[i][j]);
        __syncthreads();
    }

#pragma unroll
    for (int i = 0; i < 4; i++) {
        int mbase = m0 + wr * 64 + i * 16 + quad * 4;
#pragma unroll
        for (int j = 0; j < 4; j++) {
            int n = n0 + wc * 64 + j * 16 + l15;
#pragma unroll
            for (int r = 0; r < 4; r++) {
                float val = acc[i][j][r];
                int mm = mbase + r;
                if (mode == 3) {
                    Out[(size_t)mm * HIDDEN + n] = val;
                } else {
                    int b = mm >> 11, ss = mm & 2047;
                    int h = n >> 6, d = n & 63;
                    float vm = val * mod[n];
                    if (mode == 0) {
                        // 0.125 * log2(e): exp(s) computed as exp2 in attn
                        size_t base = ((size_t)(b * HEADS + h) * SEQ + ss) * 128;
                        Qp[base + d]      = f2bf(vm * posc[ss] * 0.18033688011112042f);
                        Qp[base + 64 + d] = f2bf(vm * poss[ss] * 0.18033688011112042f);
                    } else if (mode == 1) {
                        size_t base = ((size_t)(b * HEADS + h) * SEQ + ss) * 128;
                        Kp[base + d]      = f2bf(vm * posc[ss]);
                        Kp[base + 64 + d] = f2bf(vm * poss[ss]);
                    } else {
                        Vnt[((size_t)(b * HEADS + h) * SEQ + ss) * 64 + d] = f2bf(vm);
                    }
                }
            }
        }
    }
}

// ---------------------------------------------------------------- V shift + transpose
// grid = (bh=32, stile=32): bh fast -> same XCD as attn's consumer of Vpt[bh]
__global__ __launch_bounds__(256) void vshift_kernel(const unsigned short* __restrict__ Vnt,
                                                     unsigned short* __restrict__ Vpt) {
    __shared__ unsigned short lds[65][72];
    int bh = blockIdx.x, s0 = blockIdx.y * 64;
    int t = threadIdx.x;
    int cg = t & 15, r0 = t >> 4;
#pragma unroll
    for (int rr = 0; rr < 4; rr++) {
        int row = r0 + rr * 16;
        ushort4 v = *(const ushort4*)(Vnt + ((size_t)bh * SEQ + s0 + row) * 64 + cg * 4);
        *(ushort4*)(&lds[row][cg * 4]) = v;
    }
    if (t < 16) {
        int srow = (s0 + 64) & (SEQ - 1);
        ushort4 v = *(const ushort4*)(Vnt + ((size_t)bh * SEQ + srow) * 64 + t * 4);
        *(ushort4*)(&lds[64][t * 4]) = v;
    }
    __syncthreads();
    int d = t & 63, sb = (t >> 6) * 16;
    unsigned short outv[16];
#pragma unroll
    for (int k = 0; k < 16; k++) {
        float a = bf2f(lds[sb + k][d]), b = bf2f(lds[sb + k + 1][d]);
        outv[k] = f2bf((a + b) * 0.7071067811865476f);
    }
    unsigned short* dst = Vpt + ((size_t)bh * 64 + d) * SEQ + s0 + sb;
#pragma unroll
    for (int k = 0; k < 16; k += 4) {
        ushort4 o; o.x = outv[k]; o.y = outv[k+1]; o.z = outv[k+2]; o.w = outv[k+3];
        *(ushort4*)(dst + k) = o;
    }
}

// ---------------------------------------------------------------- flash attention
// 128-thread blocks (2 waves), 64 q/block, 32 q/wave, KT=32, double-buffered async
// staging (global_load_lds, one barrier/tile), XOR-swizzled, exp2 softmax (no max).
// LDS 29.7 KB -> ~5 blocks/CU resident; grid (bh=32, qtile=32) = 1024 blocks.
#define KT 32
#define PSTR 40    // P row stride (32+8 shorts): balanced bank spans on read
__global__ __launch_bounds__(128) void attn_kernel(const unsigned short* __restrict__ Qp,
                                                   const unsigned short* __restrict__ Kp,
                                                   const unsigned short* __restrict__ Vpt,
                                                   unsigned short* __restrict__ Ob) {
    __shared__ unsigned short Klds[2][KT * 128];     // 2 x 8 KB
    __shared__ unsigned short Vtlds[2][64 * 32];     // 2 x 4 KB
    __shared__ unsigned short Plds[2 * 32 * PSTR];   // 5120 B
    const int bh = blockIdx.x;
    const int tid = threadIdx.x, wave = tid >> 6, lane = tid & 63;
    const int quad = lane >> 4, l15 = lane & 15;
    const int q0 = blockIdx.y * 64 + wave * 32;

    short8 qf[2][4];
#pragma unroll
    for (int g = 0; g < 2; g++) {
        const unsigned short* Qbase = Qp + ((size_t)bh * SEQ + q0 + g * 16 + l15) * 128;
#pragma unroll
        for (int kk = 0; kk < 4; kk++)
            qf[g][kk] = *(const short8*)(Qbase + kk * 32 + quad * 8);
    }

    const f32x4 z4 = {0.f, 0.f, 0.f, 0.f};
    f32x4 acc[2][4];
#pragma unroll
    for (int g = 0; g < 2; g++)
#pragma unroll
        for (int dt = 0; dt < 4; dt++) acc[g][dt] = z4;
    float lsum[2][4];
#pragma unroll
    for (int g = 0; g < 2; g++)
#pragma unroll
        for (int r = 0; r < 4; r++) lsum[g][r] = 0.f;

    unsigned short* pw = &Plds[wave * 32 * PSTR];

    const unsigned short* Kbh = Kp  + (size_t)bh * SEQ * 128;
    const unsigned short* Vbh = Vpt + (size_t)bh * 64 * SEQ;

    // stage tile at key offset j into buffer buf (async; drains at next barrier)
    auto stage = [&](int j, int buf) {
#pragma unroll
        for (int p = 0; p < 4; p++) {               // K: 32 rows, 4 rows/instr
            int rb = p * 8 + wave * 4;
            int r  = rb + (lane >> 4);
            int c  = (lane & 15) ^ (r & 15);        // swizzled source chunk
            gl_lds16(Kbh + (size_t)(j + r) * 128 + c * 8, &Klds[buf][rb * 128]);
        }
#pragma unroll
        for (int p = 0; p < 2; p++) {               // V^T: 64 d-rows, 16 rows/instr
            int rb = p * 32 + wave * 16;
            int r  = rb + (lane >> 2);
            int c  = (lane & 3) ^ (r & 3);
            gl_lds16(Vbh + (size_t)r * SEQ + j + c * 8, &Vtlds[buf][rb * 32]);
        }
    };

    stage(0, 0);
    for (int it = 0; it < SEQ / KT; it++) {
        __syncthreads();                 // drains tile `it` loads; prev buf reads done
        if (it + 1 < SEQ / KT) stage((it + 1) * KT, (it + 1) & 1);   // overlap w/ compute
        const int buf = it & 1;

        // S = Q K^T over 32 keys x 32 q-rows; kf shared across both q-groups
#pragma unroll
        for (int t2 = 0; t2 < 2; t2++) {
            f32x4 sc[2] = {z4, z4};
#pragma unroll
            for (int kk = 0; kk < 4; kk++) {
                int ch = (kk * 4 + quad) ^ l15;
                short8 kf = *(const short8*)(&Klds[buf][(t2 * 16 + l15) * 128 + ch * 8]);
#pragma unroll
                for (int g = 0; g < 2; g++)
                    sc[g] = mfma16(qf[g][kk], kf, sc[g]);
            }
            // P = exp2(S) (log2e pre-folded), truncation-packed to bf16; lsum
            // accumulates the PACKED value so the pack bias cancels in num/den.
#pragma unroll
            for (int g = 0; g < 2; g++) {
#pragma unroll
                for (int r = 0; r < 4; r++) {
                    float p = __builtin_amdgcn_exp2f(sc[g][r]);
                    unsigned short pt = (unsigned short)(__builtin_bit_cast(unsigned int, p) >> 16);
                    lsum[g][r] += bf2f(pt);
                    pw[(g * 16 + quad * 4 + r) * PSTR + t2 * 16 + l15] = pt;
                }
            }
        }

        // O += P V'  (P via wave-private LDS: C->A layout); vb shared across q-groups
        {
            short8 pa0 = *(const short8*)(&pw[(l15) * PSTR + quad * 8]);
            short8 pa1 = *(const short8*)(&pw[(16 + l15) * PSTR + quad * 8]);
#pragma unroll
            for (int dt = 0; dt < 4; dt++) {
                int ch = quad ^ (l15 & 3);
                short8 vb = *(const short8*)(&Vtlds[buf][(dt * 16 + l15) * 32 + ch * 8]);
                acc[0][dt] = mfma16(pa0, vb, acc[0][dt]);
                acc[1][dt] = mfma16(pa1, vb, acc[1][dt]);
            }
        }
    }

    int b = bh >> 4, h = bh & 15;
#pragma unroll
    for (int g = 0; g < 2; g++) {
        float rinv[4];
#pragma unroll
        for (int r = 0; r < 4; r++) {
            float rs = lsum[g][r];
#pragma unroll
            for (int off = 1; off < 16; off <<= 1) rs += __shfl_xor(rs, off);
            rinv[r] = 1.0f / rs;
        }
#pragma unroll
        for (int dt = 0; dt < 4; dt++) {
#pragma unroll
            for (int r = 0; r < 4; r++) {
                int q = q0 + g * 16 + quad * 4 + r;
                int d = dt * 16 + l15;
                Ob[((size_t)(b * SEQ + q)) * HIDDEN + h * 64 + d] = f2bf(acc[g][dt][r] * rinv[r]);
            }
        }
    }
}

// ---------------------------------------------------------------- launch
extern "C" void kernel_launch(void* const* d_in, const int* in_sizes, int n_in,
                              void* d_out, int out_size, void* d_ws, size_t ws_size,
                              hipStream_t stream) {
    const float* x  = (const float*)d_in[0];
    const float* Wq = (const float*)d_in[1];
    const float* Wk = (const float*)d_in[2];
    const float* Wv = (const float*)d_in[3];
    const float* Wo = (const float*)d_in[4];
    const float* qp = (const float*)d_in[5];
    const float* qa = (const float*)d_in[6];
    char* ws = (char*)d_ws;

    unsigned short* Xb  = (unsigned short*)(ws);                      // 8 MB (reused as Ob)
    unsigned short* Wt  = (unsigned short*)(ws + (size_t)( 8 << 20)); // 8 MB (4 x 2MB, q/k/v/o)
    unsigned short* Qp_ = (unsigned short*)(ws + (size_t)(16 << 20)); // 16 MB
    unsigned short* Kp_ = (unsigned short*)(ws + (size_t)(32 << 20)); // 16 MB
    unsigned short* Vnt = (unsigned short*)(ws + (size_t)(48 << 20)); // 8 MB
    unsigned short* Vpt = (unsigned short*)(ws + (size_t)(56 << 20)); // 8 MB
    float* mod  = (float*)(ws + (size_t)(64 << 20));
    float* posc = mod + 1024;
    float* poss = posc + 2048;
    float* out  = (float*)d_out;

    convert_x_kernel<<<4096, 256, 0, stream>>>(x, Xb, qp, qa, mod, posc, poss);
    transpose_w_kernel<<<dim3(16, 16, 4), 256, 0, stream>>>(Wq, Wk, Wv, Wo, Wt);
    gemm_kernel<<<dim3(32, 8, 3), 256, 0, stream>>>(Xb, Wt, Qp_, Kp_, Vnt, out,
                                                    mod, posc, poss, 0);
    vshift_kernel<<<dim3(32, 32), 256, 0, stream>>>(Vnt, Vpt);
    attn_kernel<<<dim3(32, 32), 128, 0, stream>>>(Qp_, Kp_, Vpt, Xb /*Ob*/);
    gemm_kernel<<<dim3(32, 8, 1), 256, 0, stream>>>(Xb, Wt, Qp_, Kp_, Vnt, out,
                                                    mod, posc, poss, 3);
}

// Round 10
// 259.095 us; speedup vs baseline: 1.6606x; 1.0627x over previous
//
#include <hip/hip_runtime.h>
#include <hip/hip_bf16.h>
#include <math.h>

// Problem constants
#define HIDDEN 1024
#define HEADS  16
#define HDIM   64
#define BATCH  2
#define SEQ    2048
#define ROWS   (BATCH*SEQ)   // 4096
#define BH     (BATCH*HEADS) // 32

typedef __attribute__((ext_vector_type(8))) short  short8;
typedef __attribute__((ext_vector_type(8))) __bf16 bf16x8;
typedef __attribute__((ext_vector_type(4))) float  f32x4;

static __device__ __forceinline__ unsigned short f2bf(float f) {
    unsigned int u = __builtin_bit_cast(unsigned int, f);
    u += 0x7FFFu + ((u >> 16) & 1u);   // round-to-nearest-even
    return (unsigned short)(u >> 16);
}
static __device__ __forceinline__ float bf2f(unsigned short h) {
    unsigned int u = ((unsigned int)h) << 16;
    return __builtin_bit_cast(float, u);
}
static __device__ __forceinline__ f32x4 mfma16(short8 a, short8 b, f32x4 c) {
    return __builtin_amdgcn_mfma_f32_16x16x32_bf16(
        __builtin_bit_cast(bf16x8, a), __builtin_bit_cast(bf16x8, b), c, 0, 0, 0);
}
// async global->LDS, 16B per lane; lds dest = wave-uniform base + lane*16
static __device__ __forceinline__ void gl_lds16(const unsigned short* g, unsigned short* l) {
    __builtin_amdgcn_global_load_lds(
        (const __attribute__((address_space(1))) unsigned int*)g,
        (__attribute__((address_space(3))) unsigned int*)l, 16, 0, 0);
}

// ---------------------------------------------------------------- x -> bf16 (+ prep folded in)
__global__ void convert_x_kernel(const float* __restrict__ x, unsigned short* __restrict__ xb,
                                 const float* __restrict__ qp, const float* __restrict__ qa,
                                 float* __restrict__ mod, float* __restrict__ posc,
                                 float* __restrict__ poss) {
    int i = (blockIdx.x * 256 + threadIdx.x) * 4;
    float4 v = *(const float4*)(x + i);
    ushort4 o;
    o.x = f2bf(v.x); o.y = f2bf(v.y); o.z = f2bf(v.z); o.w = f2bf(v.w);
    *(ushort4*)(xb + i) = o;
    if (blockIdx.x < 8) {
        int k = blockIdx.x * 256 + threadIdx.x;
        if (k < HIDDEN) mod[k] = cosf(qp[k]) * qa[k];
        if (k < SEQ) {
            float ang = (float)k * (6.283185307179586f / (float)SEQ);
            posc[k] = cosf(ang);
            poss[k] = sinf(ang);
        }
    }
}

// ---------------------------------------------------------------- W -> bf16 transposed  Wt[n][k] = W[k][n]
__global__ __launch_bounds__(256) void transpose_w_kernel(
    const float* __restrict__ w0, const float* __restrict__ w1,
    const float* __restrict__ w2, const float* __restrict__ w3,
    unsigned short* __restrict__ wt) {
    __shared__ unsigned short tile[64][72];
    const float* src = (blockIdx.z == 0) ? w0 : (blockIdx.z == 1) ? w1 : (blockIdx.z == 2) ? w2 : w3;
    unsigned short* dst = wt + (size_t)blockIdx.z * HIDDEN * HIDDEN;
    int n0 = blockIdx.x * 64, k0 = blockIdx.y * 64;
    int t = threadIdx.x;
    int cg = t & 15, r0 = t >> 4;
#pragma unroll
    for (int rr = 0; rr < 4; rr++) {
        int kl = r0 + rr * 16;
        float4 v = *(const float4*)(src + (size_t)(k0 + kl) * HIDDEN + n0 + cg * 4);
        tile[cg*4+0][kl] = f2bf(v.x);
        tile[cg*4+1][kl] = f2bf(v.y);
        tile[cg*4+2][kl] = f2bf(v.z);
        tile[cg*4+3][kl] = f2bf(v.w);
    }
    __syncthreads();
#pragma unroll
    for (int rr = 0; rr < 4; rr++) {
        int nl = r0 + rr * 16;
        ushort4 o;
        o.x = tile[nl][cg*4+0]; o.y = tile[nl][cg*4+1];
        o.z = tile[nl][cg*4+2]; o.w = tile[nl][cg*4+3];
        *(ushort4*)(dst + (size_t)(n0 + nl) * HIDDEN + k0 + cg * 4) = o;
    }
}

// ---------------------------------------------------------------- GEMM (BK=64, XOR swizzle)
// modes 0..2: C -> plain row-major bf16 buffer (rearrangement done by later passes).
// mode 3: fp32 -> Out. grid = (mtiles=32, ntiles=8, z): id%8 -> XCD-pinned A-row-tile.
__global__ __launch_bounds__(256) void gemm_kernel(
    const unsigned short* __restrict__ A, const unsigned short* __restrict__ WtBase,
    unsigned short* __restrict__ CBase, float* __restrict__ Out, int mode0) {
    __shared__ unsigned short Alds[128 * 64];   // 16 KB
    __shared__ unsigned short Blds[128 * 64];   // 16 KB
    const int mode = mode0 + blockIdx.z;
    const unsigned short* Bt = WtBase + (size_t)mode * HIDDEN * HIDDEN;
    unsigned short* Cout = CBase + (size_t)mode * ROWS * HIDDEN;
    const int m0 = blockIdx.x * 128, n0 = blockIdx.y * 128;
    const int tid = threadIdx.x;
    const int wave = tid >> 6, lane = tid & 63, quad = lane >> 4, l15 = lane & 15;
    const int wr = wave >> 1, wc = wave & 1;
    const int srow = lane >> 3;
    const int schunk = (lane & 7) ^ (srow & 7);          // swizzled source chunk

    f32x4 acc[4][4];
    const f32x4 z4 = {0.f, 0.f, 0.f, 0.f};
#pragma unroll
    for (int i = 0; i < 4; i++)
#pragma unroll
        for (int j = 0; j < 4; j++) acc[i][j] = z4;

    for (int k0 = 0; k0 < HIDDEN; k0 += 64) {
#pragma unroll
        for (int p = 0; p < 4; p++) {
            int rbase = p * 32 + wave * 8;
            gl_lds16(A  + (size_t)(m0 + rbase + srow) * HIDDEN + k0 + schunk * 8,
                     &Alds[rbase * 64]);
            gl_lds16(Bt + (size_t)(n0 + rbase + srow) * HIDDEN + k0 + schunk * 8,
                     &Blds[rbase * 64]);
        }
        __syncthreads();
        short8 aF[4][2], bF[4][2];
#pragma unroll
        for (int h = 0; h < 2; h++) {
#pragma unroll
            for (int i = 0; i < 4; i++) {
                int row = wr * 64 + i * 16 + l15;
                aF[i][h] = *(const short8*)(&Alds[row * 64 + ((h * 4 + quad) ^ (l15 & 7)) * 8]);
            }
#pragma unroll
            for (int j = 0; j < 4; j++) {
                int row = wc * 64 + j * 16 + l15;
                bF[j][h] = *(const short8*)(&Blds[row * 64 + ((h * 4 + quad) ^ (l15 & 7)) * 8]);
            }
        }
#pragma unroll
        for (int h = 0; h < 2; h++)
#pragma unroll
            for (int i = 0; i < 4; i++)
#pragma unroll
                for (int j = 0; j < 4; j++)
                    acc[i][j] = mfma16(aF[i][h], bF[j][h], acc[i][j]);
        __syncthreads();
    }

#pragma unroll
    for (int i = 0; i < 4; i++) {
        int mbase = m0 + wr * 64 + i * 16 + quad * 4;
#pragma unroll
        for (int j = 0; j < 4; j++) {
            int n = n0 + wc * 64 + j * 16 + l15;
#pragma unroll
            for (int r = 0; r < 4; r++) {
                float val = acc[i][j][r];
                int mm = mbase + r;
                if (mode == 3) Out[(size_t)mm * HIDDEN + n] = val;
                else           Cout[(size_t)mm * HIDDEN + n] = f2bf(val);
            }
        }
    }
}

// ---------------------------------------------------------------- K rearrange: Ck -> Kp
// Kp[bh][ss][d] = Ck[b*S+ss][h*64+d]*mod*posc[ss], [d+64] with poss. Coalesced 16B both sides.
// grid = (bh=32, stile=16), 256 thr: thread = (row pair-half).
__global__ __launch_bounds__(256) void k_rearrange(const unsigned short* __restrict__ Ck,
                                                   unsigned short* __restrict__ Kp,
                                                   const float* __restrict__ mod,
                                                   const float* __restrict__ posc,
                                                   const float* __restrict__ poss) {
    int bh = blockIdx.x, b = bh >> 4, h = bh & 15;
    int t = threadIdx.x;
    int ss = blockIdx.y * 128 + (t >> 1);
    int half = (t & 1) * 32;
    const unsigned short* src = Ck + ((size_t)(b * SEQ + ss)) * HIDDEN + h * 64 + half;
    unsigned short* dst = Kp + ((size_t)bh * SEQ + ss) * 128 + half;
    float pc = posc[ss], ps = poss[ss];
#pragma unroll
    for (int c8 = 0; c8 < 4; c8++) {
        short8 u = *(const short8*)(src + c8 * 8);
        short8 o0, o1;
#pragma unroll
        for (int e = 0; e < 8; e++) {
            float f = bf2f((unsigned short)u[e]) * mod[h * 64 + half + c8 * 8 + e];
            o0[e] = (short)f2bf(f * pc);
            o1[e] = (short)f2bf(f * ps);
        }
        *(short8*)(dst + c8 * 8) = o0;
        *(short8*)(dst + 64 + c8 * 8) = o1;
    }
}

// ---------------------------------------------------------------- V: mod + shift + transpose
// Vpt[bh][d][s] = (Vm[s][d] + Vm[(s+1)%S][d])/sqrt2, Vm = Cv*mod. grid = (bh=32, stile=32).
__global__ __launch_bounds__(256) void vmod_shift(const unsigned short* __restrict__ Cv,
                                                  unsigned short* __restrict__ Vpt,
                                                  const float* __restrict__ mod) {
    __shared__ unsigned short lds[65][72];
    int bh = blockIdx.x, b = bh >> 4, h = bh & 15;
    int s0 = blockIdx.y * 64;
    int t = threadIdx.x;
    int cg = t & 15, r0 = t >> 4;
    const float4 m4 = *(const float4*)(mod + h * 64 + cg * 4);
#pragma unroll
    for (int rr = 0; rr < 4; rr++) {
        int row = r0 + rr * 16;
        ushort4 v = *(const ushort4*)(Cv + ((size_t)(b * SEQ + s0 + row)) * HIDDEN + h * 64 + cg * 4);
        lds[row][cg*4+0] = f2bf(bf2f(v.x) * m4.x);
        lds[row][cg*4+1] = f2bf(bf2f(v.y) * m4.y);
        lds[row][cg*4+2] = f2bf(bf2f(v.z) * m4.z);
        lds[row][cg*4+3] = f2bf(bf2f(v.w) * m4.w);
    }
    if (t < 16) {
        int srow = (s0 + 64) & (SEQ - 1);
        const float4 mm4 = *(const float4*)(mod + h * 64 + t * 4);
        ushort4 v = *(const ushort4*)(Cv + ((size_t)(b * SEQ + srow)) * HIDDEN + h * 64 + t * 4);
        lds[64][t*4+0] = f2bf(bf2f(v.x) * mm4.x);
        lds[64][t*4+1] = f2bf(bf2f(v.y) * mm4.y);
        lds[64][t*4+2] = f2bf(bf2f(v.z) * mm4.z);
        lds[64][t*4+3] = f2bf(bf2f(v.w) * mm4.w);
    }
    __syncthreads();
    int d = t & 63, sb = (t >> 6) * 16;
    unsigned short outv[16];
#pragma unroll
    for (int k = 0; k < 16; k++) {
        float a = bf2f(lds[sb + k][d]), bb = bf2f(lds[sb + k + 1][d]);
        outv[k] = f2bf((a + bb) * 0.7071067811865476f);
    }
    unsigned short* dst = Vpt + ((size_t)bh * 64 + d) * SEQ + s0 + sb;
#pragma unroll
    for (int k = 0; k < 16; k += 4) {
        ushort4 o; o.x = outv[k]; o.y = outv[k+1]; o.z = outv[k+2]; o.w = outv[k+3];
        *(ushort4*)(dst + k) = o;
    }
}

// ---------------------------------------------------------------- flash attention (R7 body)
// Q loaded once per block from plain Cq with on-the-fly mod/pos/scale (no Qp buffer).
// 32 q/wave, hoisted K/V fragments, exp2 softmax, double-buffered async staging, swizzled.
// grid = (bh=32, qtile=16) = 512 blocks; bh fast -> per-XCD K/V L2 residency.
#define KT 64
#define PSTR 76    // P row stride: quad bank offsets {0,24,16,8} -> <=2-way
__global__ __launch_bounds__(256) void attn_kernel(const unsigned short* __restrict__ Cq,
                                                   const unsigned short* __restrict__ Kp,
                                                   const unsigned short* __restrict__ Vpt,
                                                   unsigned short* __restrict__ Ob,
                                                   const float* __restrict__ mod,
                                                   const float* __restrict__ posc,
                                                   const float* __restrict__ poss) {
    __shared__ unsigned short Klds[2][KT * 128];     // 2 x 16 KB, unpadded
    __shared__ unsigned short Vtlds[2][64 * 64];     // 2 x 8 KB, unpadded
    __shared__ unsigned short Plds[4 * 32 * PSTR];   // 19456 B
    const int bh = blockIdx.x;
    const int b = bh >> 4, h = bh & 15;
    const int tid = threadIdx.x, wave = tid >> 6, lane = tid & 63;
    const int quad = lane >> 4, l15 = lane & 15;
    const int q0 = blockIdx.y * 128 + wave * 32;

    // Q fragments from plain C: col c = kk*32+quad*8+e; c<64 -> d=c (posc), else d=c-64 (poss).
    short8 qf[2][4];
#pragma unroll
    for (int g = 0; g < 2; g++) {
        int ss = q0 + g * 16 + l15;
        const unsigned short* crow = Cq + ((size_t)(b * SEQ + ss)) * HIDDEN + h * 64;
        float pc = posc[ss] * 0.18033688011112042f;   // 0.125*log2(e)
        float ps = poss[ss] * 0.18033688011112042f;
#pragma unroll
        for (int kk = 0; kk < 4; kk++) {
            int bd = (kk & 1) * 32 + quad * 8;
            short8 u = *(const short8*)(crow + bd);
            float sc = (kk < 2) ? pc : ps;
            short8 q;
#pragma unroll
            for (int e = 0; e < 8; e++)
                q[e] = (short)f2bf(bf2f((unsigned short)u[e]) * mod[h * 64 + bd + e] * sc);
            qf[g][kk] = q;
        }
    }

    const f32x4 z4 = {0.f, 0.f, 0.f, 0.f};
    f32x4 acc[2][4];
#pragma unroll
    for (int g = 0; g < 2; g++)
#pragma unroll
        for (int dt = 0; dt < 4; dt++) acc[g][dt] = z4;
    float lsum[2][4];
#pragma unroll
    for (int g = 0; g < 2; g++)
#pragma unroll
        for (int r = 0; r < 4; r++) lsum[g][r] = 0.f;

    unsigned short* pw = &Plds[wave * 32 * PSTR];

    const unsigned short* Kbh = Kp  + (size_t)bh * SEQ * 128;
    const unsigned short* Vbh = Vpt + (size_t)bh * 64 * SEQ;

    auto stage = [&](int j, int buf) {
#pragma unroll
        for (int p = 0; p < 4; p++) {               // K: 4 passes of 16 rows
            int rb = p * 16 + wave * 4;
            int r  = rb + (lane >> 4);
            int c  = (lane & 15) ^ (r & 15);        // swizzled source chunk
            gl_lds16(Kbh + (size_t)(j + r) * 128 + c * 8, &Klds[buf][rb * 128]);
        }
#pragma unroll
        for (int p = 0; p < 2; p++) {               // V^T: 2 passes of 32 d-rows
            int rb = p * 32 + wave * 8;
            int r  = rb + (lane >> 3);
            int c  = (lane & 7) ^ (r & 7);
            gl_lds16(Vbh + (size_t)r * SEQ + j + c * 8, &Vtlds[buf][rb * 64]);
        }
    };

    stage(0, 0);
    for (int it = 0; it < SEQ / KT; it++) {
        __syncthreads();                 // drains tile `it` loads; prev buf reads done
        if (it + 1 < SEQ / KT) stage((it + 1) * KT, (it + 1) & 1);   // overlap w/ compute
        const int buf = it & 1;

        // S = Q K^T over 64 keys x 32 q-rows; kf shared across both q-groups
#pragma unroll
        for (int t2 = 0; t2 < 4; t2++) {
            f32x4 sc[2] = {z4, z4};
#pragma unroll
            for (int kk = 0; kk < 4; kk++) {
                int ch = (kk * 4 + quad) ^ l15;
                short8 kf = *(const short8*)(&Klds[buf][(t2 * 16 + l15) * 128 + ch * 8]);
#pragma unroll
                for (int g = 0; g < 2; g++)
                    sc[g] = mfma16(qf[g][kk], kf, sc[g]);
            }
            // P = exp2(S), truncation-packed; lsum sums the PACKED value (bias cancels).
#pragma unroll
            for (int g = 0; g < 2; g++) {
#pragma unroll
                for (int r = 0; r < 4; r++) {
                    float p = __builtin_amdgcn_exp2f(sc[g][r]);
                    unsigned short pt = (unsigned short)(__builtin_bit_cast(unsigned int, p) >> 16);
                    lsum[g][r] += bf2f(pt);
                    pw[(g * 16 + quad * 4 + r) * PSTR + t2 * 16 + l15] = pt;
                }
            }
        }

        // O += P V'  (P via wave-private LDS: C->A layout); vb shared across q-groups
#pragma unroll
        for (int pt = 0; pt < 2; pt++) {
            short8 pa0 = *(const short8*)(&pw[(l15) * PSTR + pt * 32 + quad * 8]);
            short8 pa1 = *(const short8*)(&pw[(16 + l15) * PSTR + pt * 32 + quad * 8]);
#pragma unroll
            for (int dt = 0; dt < 4; dt++) {
                int ch = (pt * 4 + quad) ^ (l15 & 7);
                short8 vb = *(const short8*)(&Vtlds[buf][(dt * 16 + l15) * 64 + ch * 8]);
                acc[0][dt] = mfma16(pa0, vb, acc[0][dt]);
                acc[1][dt] = mfma16(pa1, vb, acc[1][dt]);
            }
        }
    }

#pragma unroll
    for (int g = 0; g < 2; g++) {
        float rinv[4];
#pragma unroll
        for (int r = 0; r < 4; r++) {
            float rs = lsum[g][r];
#pragma unroll
            for (int off = 1; off < 16; off <<= 1) rs += __shfl_xor(rs, off);
            rinv[r] = 1.0f / rs;
        }
#pragma unroll
        for (int dt = 0; dt < 4; dt++) {
#pragma unroll
            for (int r = 0; r < 4; r++) {
                int q = q0 + g * 16 + quad * 4 + r;
                int d = dt * 16 + l15;
                Ob[((size_t)(b * SEQ + q)) * HIDDEN + h * 64 + d] = f2bf(acc[g][dt][r] * rinv[r]);
            }
        }
    }
}

// ---------------------------------------------------------------- launch
extern "C" void kernel_launch(void* const* d_in, const int* in_sizes, int n_in,
                              void* d_out, int out_size, void* d_ws, size_t ws_size,
                              hipStream_t stream) {
    const float* x  = (const float*)d_in[0];
    const float* Wq = (const float*)d_in[1];
    const float* Wk = (const float*)d_in[2];
    const float* Wv = (const float*)d_in[3];
    const float* Wo = (const float*)d_in[4];
    const float* qp = (const float*)d_in[5];
    const float* qa = (const float*)d_in[6];
    char* ws = (char*)d_ws;

    unsigned short* Xb  = (unsigned short*)(ws);                      // 8 MB (reused as Ob)
    unsigned short* Wt  = (unsigned short*)(ws + (size_t)( 8 << 20)); // 8 MB (4 x 2MB, q/k/v/o)
    unsigned short* Cq  = (unsigned short*)(ws + (size_t)(16 << 20)); // 8 MB  (+Ck at 24M, Cv at 32M)
    unsigned short* Ck  = (unsigned short*)(ws + (size_t)(24 << 20)); // 8 MB
    unsigned short* Cv  = (unsigned short*)(ws + (size_t)(32 << 20)); // 8 MB
    unsigned short* Kp_ = (unsigned short*)(ws + (size_t)(40 << 20)); // 16 MB
    unsigned short* Vpt = (unsigned short*)(ws + (size_t)(56 << 20)); // 8 MB
    float* mod  = (float*)(ws + (size_t)(64 << 20));
    float* posc = mod + 1024;
    float* poss = posc + 2048;
    float* out  = (float*)d_out;

    convert_x_kernel<<<4096, 256, 0, stream>>>(x, Xb, qp, qa, mod, posc, poss);
    transpose_w_kernel<<<dim3(16, 16, 4), 256, 0, stream>>>(Wq, Wk, Wv, Wo, Wt);
    gemm_kernel<<<dim3(32, 8, 3), 256, 0, stream>>>(Xb, Wt, Cq, out, 0);   // -> Cq,Ck,Cv
    k_rearrange<<<dim3(32, 16), 256, 0, stream>>>(Ck, Kp_, mod, posc, poss);
    vmod_shift<<<dim3(32, 32), 256, 0, stream>>>(Cv, Vpt, mod);
    attn_kernel<<<dim3(32, 16), 256, 0, stream>>>(Cq, Kp_, Vpt, Xb /*Ob*/, mod, posc, poss);
    gemm_kernel<<<dim3(32, 8, 1), 256, 0, stream>>>(Xb, Wt, Cq, out, 3);   // O-proj -> out
}

// Round 11
// 254.722 us; speedup vs baseline: 1.6891x; 1.0172x over previous
//
#include <hip/hip_runtime.h>
#include <hip/hip_bf16.h>
#include <math.h>

// Problem constants
#define HIDDEN 1024
#define HEADS  16
#define HDIM   64
#define BATCH  2
#define SEQ    2048
#define ROWS   (BATCH*SEQ)   // 4096
#define BH     (BATCH*HEADS) // 32

typedef __attribute__((ext_vector_type(8))) short  short8;
typedef __attribute__((ext_vector_type(8))) __bf16 bf16x8;
typedef __attribute__((ext_vector_type(4))) float  f32x4;

static __device__ __forceinline__ unsigned short f2bf(float f) {
    unsigned int u = __builtin_bit_cast(unsigned int, f);
    u += 0x7FFFu + ((u >> 16) & 1u);   // round-to-nearest-even
    return (unsigned short)(u >> 16);
}
static __device__ __forceinline__ float bf2f(unsigned short h) {
    unsigned int u = ((unsigned int)h) << 16;
    return __builtin_bit_cast(float, u);
}
static __device__ __forceinline__ f32x4 mfma16(short8 a, short8 b, f32x4 c) {
    return __builtin_amdgcn_mfma_f32_16x16x32_bf16(
        __builtin_bit_cast(bf16x8, a), __builtin_bit_cast(bf16x8, b), c, 0, 0, 0);
}
// async global->LDS, 16B per lane; lds dest = wave-uniform base + lane*16
static __device__ __forceinline__ void gl_lds16(const unsigned short* g, unsigned short* l) {
    __builtin_amdgcn_global_load_lds(
        (const __attribute__((address_space(1))) unsigned int*)g,
        (__attribute__((address_space(3))) unsigned int*)l, 16, 0, 0);
}

// ---------------------------------------------------------------- x -> bf16 (+ prep folded in)
// mod[d]  = cos(qp)*qa                      (for V path)
// mod2[d] = mod[d]^2 * 0.125 * log2(e)      (for Q path; K stays raw)
__global__ void convert_x_kernel(const float* __restrict__ x, unsigned short* __restrict__ xb,
                                 const float* __restrict__ qp, const float* __restrict__ qa,
                                 float* __restrict__ mod, float* __restrict__ mod2,
                                 float* __restrict__ posc, float* __restrict__ poss) {
    int i = (blockIdx.x * 256 + threadIdx.x) * 4;
    float4 v = *(const float4*)(x + i);
    ushort4 o;
    o.x = f2bf(v.x); o.y = f2bf(v.y); o.z = f2bf(v.z); o.w = f2bf(v.w);
    *(ushort4*)(xb + i) = o;
    if (blockIdx.x < 8) {
        int k = blockIdx.x * 256 + threadIdx.x;
        if (k < HIDDEN) {
            float m = cosf(qp[k]) * qa[k];
            mod[k] = m;
            mod2[k] = m * m * 0.18033688011112042f;
        }
        if (k < SEQ) {
            float ang = (float)k * (6.283185307179586f / (float)SEQ);
            posc[k] = cosf(ang);
            poss[k] = sinf(ang);
        }
    }
}

// ---------------------------------------------------------------- W -> bf16 transposed  Wt[n][k] = W[k][n]
__global__ __launch_bounds__(256) void transpose_w_kernel(
    const float* __restrict__ w0, const float* __restrict__ w1,
    const float* __restrict__ w2, const float* __restrict__ w3,
    unsigned short* __restrict__ wt) {
    __shared__ unsigned short tile[64][72];
    const float* src = (blockIdx.z == 0) ? w0 : (blockIdx.z == 1) ? w1 : (blockIdx.z == 2) ? w2 : w3;
    unsigned short* dst = wt + (size_t)blockIdx.z * HIDDEN * HIDDEN;
    int n0 = blockIdx.x * 64, k0 = blockIdx.y * 64;
    int t = threadIdx.x;
    int cg = t & 15, r0 = t >> 4;
#pragma unroll
    for (int rr = 0; rr < 4; rr++) {
        int kl = r0 + rr * 16;
        float4 v = *(const float4*)(src + (size_t)(k0 + kl) * HIDDEN + n0 + cg * 4);
        tile[cg*4+0][kl] = f2bf(v.x);
        tile[cg*4+1][kl] = f2bf(v.y);
        tile[cg*4+2][kl] = f2bf(v.z);
        tile[cg*4+3][kl] = f2bf(v.w);
    }
    __syncthreads();
#pragma unroll
    for (int rr = 0; rr < 4; rr++) {
        int nl = r0 + rr * 16;
        ushort4 o;
        o.x = tile[nl][cg*4+0]; o.y = tile[nl][cg*4+1];
        o.z = tile[nl][cg*4+2]; o.w = tile[nl][cg*4+3];
        *(ushort4*)(dst + (size_t)(n0 + nl) * HIDDEN + k0 + cg * 4) = o;
    }
}

// ---------------------------------------------------------------- GEMM (BK=64, XOR swizzle)
// modes 0..2: C -> plain row-major bf16 buffer. mode 3: fp32 -> Out.
// grid = (mtiles=32, ntiles=8, z): id%8 -> XCD-pinned A-row-tile.
__global__ __launch_bounds__(256) void gemm_kernel(
    const unsigned short* __restrict__ A, const unsigned short* __restrict__ WtBase,
    unsigned short* __restrict__ CBase, float* __restrict__ Out, int mode0) {
    __shared__ unsigned short Alds[128 * 64];   // 16 KB
    __shared__ unsigned short Blds[128 * 64];   // 16 KB
    const int mode = mode0 + blockIdx.z;
    const unsigned short* Bt = WtBase + (size_t)mode * HIDDEN * HIDDEN;
    unsigned short* Cout = CBase + (size_t)mode * ROWS * HIDDEN;
    const int m0 = blockIdx.x * 128, n0 = blockIdx.y * 128;
    const int tid = threadIdx.x;
    const int wave = tid >> 6, lane = tid & 63, quad = lane >> 4, l15 = lane & 15;
    const int wr = wave >> 1, wc = wave & 1;
    const int srow = lane >> 3;
    const int schunk = (lane & 7) ^ (srow & 7);          // swizzled source chunk

    f32x4 acc[4][4];
    const f32x4 z4 = {0.f, 0.f, 0.f, 0.f};
#pragma unroll
    for (int i = 0; i < 4; i++)
#pragma unroll
        for (int j = 0; j < 4; j++) acc[i][j] = z4;

    for (int k0 = 0; k0 < HIDDEN; k0 += 64) {
#pragma unroll
        for (int p = 0; p < 4; p++) {
            int rbase = p * 32 + wave * 8;
            gl_lds16(A  + (size_t)(m0 + rbase + srow) * HIDDEN + k0 + schunk * 8,
                     &Alds[rbase * 64]);
            gl_lds16(Bt + (size_t)(n0 + rbase + srow) * HIDDEN + k0 + schunk * 8,
                     &Blds[rbase * 64]);
        }
        __syncthreads();
        short8 aF[4][2], bF[4][2];
#pragma unroll
        for (int h = 0; h < 2; h++) {
#pragma unroll
            for (int i = 0; i < 4; i++) {
                int row = wr * 64 + i * 16 + l15;
                aF[i][h] = *(const short8*)(&Alds[row * 64 + ((h * 4 + quad) ^ (l15 & 7)) * 8]);
            }
#pragma unroll
            for (int j = 0; j < 4; j++) {
                int row = wc * 64 + j * 16 + l15;
                bF[j][h] = *(const short8*)(&Blds[row * 64 + ((h * 4 + quad) ^ (l15 & 7)) * 8]);
            }
        }
#pragma unroll
        for (int h = 0; h < 2; h++)
#pragma unroll
            for (int i = 0; i < 4; i++)
#pragma unroll
                for (int j = 0; j < 4; j++)
                    acc[i][j] = mfma16(aF[i][h], bF[j][h], acc[i][j]);
        __syncthreads();
    }

#pragma unroll
    for (int i = 0; i < 4; i++) {
        int mbase = m0 + wr * 64 + i * 16 + quad * 4;
#pragma unroll
        for (int j = 0; j < 4; j++) {
            int n = n0 + wc * 64 + j * 16 + l15;
#pragma unroll
            for (int r = 0; r < 4; r++) {
                float val = acc[i][j][r];
                int mm = mbase + r;
                if (mode == 3) Out[(size_t)mm * HIDDEN + n] = val;
                else           Cout[(size_t)mm * HIDDEN + n] = f2bf(val);
            }
        }
    }
}

// ---------------------------------------------------------------- V: mod + shift + transpose
// Vpt[bh][d][s] = (Vm[s][d] + Vm[(s+1)%S][d])/sqrt2, Vm = Cv*mod. grid = (bh=32, stile=32).
__global__ __launch_bounds__(256) void vmod_shift(const unsigned short* __restrict__ Cv,
                                                  unsigned short* __restrict__ Vpt,
                                                  const float* __restrict__ mod) {
    __shared__ unsigned short lds[65][72];
    int bh = blockIdx.x, b = bh >> 4, h = bh & 15;
    int s0 = blockIdx.y * 64;
    int t = threadIdx.x;
    int cg = t & 15, r0 = t >> 4;
    const float4 m4 = *(const float4*)(mod + h * 64 + cg * 4);
#pragma unroll
    for (int rr = 0; rr < 4; rr++) {
        int row = r0 + rr * 16;
        ushort4 v = *(const ushort4*)(Cv + ((size_t)(b * SEQ + s0 + row)) * HIDDEN + h * 64 + cg * 4);
        lds[row][cg*4+0] = f2bf(bf2f(v.x) * m4.x);
        lds[row][cg*4+1] = f2bf(bf2f(v.y) * m4.y);
        lds[row][cg*4+2] = f2bf(bf2f(v.z) * m4.z);
        lds[row][cg*4+3] = f2bf(bf2f(v.w) * m4.w);
    }
    if (t < 16) {
        int srow = (s0 + 64) & (SEQ - 1);
        const float4 mm4 = *(const float4*)(mod + h * 64 + t * 4);
        ushort4 v = *(const ushort4*)(Cv + ((size_t)(b * SEQ + srow)) * HIDDEN + h * 64 + t * 4);
        lds[64][t*4+0] = f2bf(bf2f(v.x) * mm4.x);
        lds[64][t*4+1] = f2bf(bf2f(v.y) * mm4.y);
        lds[64][t*4+2] = f2bf(bf2f(v.z) * mm4.z);
        lds[64][t*4+3] = f2bf(bf2f(v.w) * mm4.w);
    }
    __syncthreads();
    int d = t & 63, sb = (t >> 6) * 16;
    unsigned short outv[16];
#pragma unroll
    for (int k = 0; k < 16; k++) {
        float a = bf2f(lds[sb + k][d]), bb = bf2f(lds[sb + k + 1][d]);
        outv[k] = f2bf((a + bb) * 0.7071067811865476f);
    }
    unsigned short* dst = Vpt + ((size_t)bh * 64 + d) * SEQ + s0 + sb;
#pragma unroll
    for (int k = 0; k < 16; k += 4) {
        ushort4 o; o.x = outv[k]; o.y = outv[k+1]; o.z = outv[k+2]; o.w = outv[k+3];
        *(ushort4*)(dst + k) = o;
    }
}

// ---------------------------------------------------------------- flash attention (D=64 QK + scalar interference)
// S_ij = sigma_ij * (c_i c_j + s_i s_j), sigma = q.k with mod^2*0.125*log2e folded into q.
// K staged DIRECTLY from plain Ck (no Kp buffer), D=64 -> QK MFMAs halved vs D=128.
// LDS 51.4 KB -> 3 blocks/CU. Double-buffered async staging, XOR-swizzled, exp2 softmax.
// grid = (bh=32, qtile=16) = 512 blocks; bh fast -> per-XCD K/V L2 residency.
#define KT 64
#define PSTR 76    // P row stride: quad bank offsets {0,24,16,8} -> <=2-way
__global__ __launch_bounds__(256) void attn_kernel(const unsigned short* __restrict__ Cq,
                                                   const unsigned short* __restrict__ Ck,
                                                   const unsigned short* __restrict__ Vpt,
                                                   unsigned short* __restrict__ Ob,
                                                   const float* __restrict__ mod2,
                                                   const float* __restrict__ posc,
                                                   const float* __restrict__ poss) {
    __shared__ unsigned short Klds[2][KT * 64];      // 2 x 8 KB, unpadded
    __shared__ unsigned short Vtlds[2][64 * 64];     // 2 x 8 KB, unpadded
    __shared__ unsigned short Plds[4 * 32 * PSTR];   // 19456 B
    const int bh = blockIdx.x;
    const int b = bh >> 4, h = bh & 15;
    const int tid = threadIdx.x, wave = tid >> 6, lane = tid & 63;
    const int quad = lane >> 4, l15 = lane & 15;
    const int q0 = blockIdx.y * 128 + wave * 32;

    // Q fragments (D=64): q'_d = Cq_d * mod2_d   (mod^2 and 0.125*log2e folded)
    short8 qf[2][2];
#pragma unroll
    for (int g = 0; g < 2; g++) {
        int ss = q0 + g * 16 + l15;
        const unsigned short* crow = Cq + ((size_t)(b * SEQ + ss)) * HIDDEN + h * 64;
#pragma unroll
        for (int kk = 0; kk < 2; kk++) {
            int bd = kk * 32 + quad * 8;
            short8 u = *(const short8*)(crow + bd);
            short8 q;
#pragma unroll
            for (int e = 0; e < 8; e++)
                q[e] = (short)f2bf(bf2f((unsigned short)u[e]) * mod2[h * 64 + bd + e]);
            qf[g][kk] = q;
        }
    }
    // per-q-row interference factors c_i, s_i (rows quad*4+r in C layout)
    float ci[2][4], si[2][4];
#pragma unroll
    for (int g = 0; g < 2; g++)
#pragma unroll
        for (int r = 0; r < 4; r++) {
            int ss = q0 + g * 16 + quad * 4 + r;
            ci[g][r] = posc[ss];
            si[g][r] = poss[ss];
        }

    const f32x4 z4 = {0.f, 0.f, 0.f, 0.f};
    f32x4 acc[2][4];
#pragma unroll
    for (int g = 0; g < 2; g++)
#pragma unroll
        for (int dt = 0; dt < 4; dt++) acc[g][dt] = z4;
    float lsum[2][4];
#pragma unroll
    for (int g = 0; g < 2; g++)
#pragma unroll
        for (int r = 0; r < 4; r++) lsum[g][r] = 0.f;

    unsigned short* pw = &Plds[wave * 32 * PSTR];

    const unsigned short* Kbh = Ck  + ((size_t)b * SEQ) * HIDDEN + h * 64;  // row stride HIDDEN
    const unsigned short* Vbh = Vpt + (size_t)bh * 64 * SEQ;

    auto stage = [&](int j, int buf) {
#pragma unroll
        for (int p = 0; p < 2; p++) {               // K: 64 rows x 64 shorts, 8 rows/instr
            int rb = p * 32 + wave * 8;
            int r  = rb + (lane >> 3);
            int c  = (lane & 7) ^ (r & 7);          // swizzled source chunk
            gl_lds16(Kbh + (size_t)(j + r) * HIDDEN + c * 8, &Klds[buf][rb * 64]);
        }
#pragma unroll
        for (int p = 0; p < 2; p++) {               // V^T: 2 passes of 32 d-rows
            int rb = p * 32 + wave * 8;
            int r  = rb + (lane >> 3);
            int c  = (lane & 7) ^ (r & 7);
            gl_lds16(Vbh + (size_t)r * SEQ + j + c * 8, &Vtlds[buf][rb * 64]);
        }
    };

    stage(0, 0);
    for (int it = 0; it < SEQ / KT; it++) {
        const int j0 = it * KT;
        __syncthreads();                 // drains tile `it` loads; prev buf reads done
        if (it + 1 < SEQ / KT) stage((it + 1) * KT, (it + 1) & 1);   // overlap w/ compute
        const int buf = it & 1;

        // sigma = Q K^T (D=64) over 64 keys x 32 q-rows; kf shared across q-groups
#pragma unroll
        for (int t2 = 0; t2 < 4; t2++) {
            // key-col factors for this subtile (lane l15 = key col)
            float cj = posc[j0 + t2 * 16 + l15];
            float sj = poss[j0 + t2 * 16 + l15];
            f32x4 sc[2] = {z4, z4};
#pragma unroll
            for (int kk = 0; kk < 2; kk++) {
                int ch = (kk * 4 + quad) ^ (l15 & 7);
                short8 kf = *(const short8*)(&Klds[buf][(t2 * 16 + l15) * 64 + ch * 8]);
#pragma unroll
                for (int g = 0; g < 2; g++)
                    sc[g] = mfma16(qf[g][kk], kf, sc[g]);
            }
            // P = exp2(sigma * (ci*cj + si*sj)); truncation-packed; lsum sums PACKED value.
#pragma unroll
            for (int g = 0; g < 2; g++) {
#pragma unroll
                for (int r = 0; r < 4; r++) {
                    float w = ci[g][r] * cj + si[g][r] * sj;
                    float p = __builtin_amdgcn_exp2f(sc[g][r] * w);
                    unsigned short pt = (unsigned short)(__builtin_bit_cast(unsigned int, p) >> 16);
                    lsum[g][r] += bf2f(pt);
                    pw[(g * 16 + quad * 4 + r) * PSTR + t2 * 16 + l15] = pt;
                }
            }
        }

        // O += P V'  (P via wave-private LDS: C->A layout); vb shared across q-groups
#pragma unroll
        for (int pt = 0; pt < 2; pt++) {
            short8 pa0 = *(const short8*)(&pw[(l15) * PSTR + pt * 32 + quad * 8]);
            short8 pa1 = *(const short8*)(&pw[(16 + l15) * PSTR + pt * 32 + quad * 8]);
#pragma unroll
            for (int dt = 0; dt < 4; dt++) {
                int ch = (pt * 4 + quad) ^ (l15 & 7);
                short8 vb = *(const short8*)(&Vtlds[buf][(dt * 16 + l15) * 64 + ch * 8]);
                acc[0][dt] = mfma16(pa0, vb, acc[0][dt]);
                acc[1][dt] = mfma16(pa1, vb, acc[1][dt]);
            }
        }
    }

#pragma unroll
    for (int g = 0; g < 2; g++) {
        float rinv[4];
#pragma unroll
        for (int r = 0; r < 4; r++) {
            float rs = lsum[g][r];
#pragma unroll
            for (int off = 1; off < 16; off <<= 1) rs += __shfl_xor(rs, off);
            rinv[r] = 1.0f / rs;
        }
#pragma unroll
        for (int dt = 0; dt < 4; dt++) {
#pragma unroll
            for (int r = 0; r < 4; r++) {
                int q = q0 + g * 16 + quad * 4 + r;
                int d = dt * 16 + l15;
                Ob[((size_t)(b * SEQ + q)) * HIDDEN + h * 64 + d] = f2bf(acc[g][dt][r] * rinv[r]);
            }
        }
    }
}

// ---------------------------------------------------------------- launch
extern "C" void kernel_launch(void* const* d_in, const int* in_sizes, int n_in,
                              void* d_out, int out_size, void* d_ws, size_t ws_size,
                              hipStream_t stream) {
    const float* x  = (const float*)d_in[0];
    const float* Wq = (const float*)d_in[1];
    const float* Wk = (const float*)d_in[2];
    const float* Wv = (const float*)d_in[3];
    const float* Wo = (const float*)d_in[4];
    const float* qp = (const float*)d_in[5];
    const float* qa = (const float*)d_in[6];
    char* ws = (char*)d_ws;

    unsigned short* Xb  = (unsigned short*)(ws);                      // 8 MB (reused as Ob)
    unsigned short* Wt  = (unsigned short*)(ws + (size_t)( 8 << 20)); // 8 MB (4 x 2MB)
    unsigned short* Cq  = (unsigned short*)(ws + (size_t)(16 << 20)); // 8 MB
    unsigned short* Ck  = (unsigned short*)(ws + (size_t)(24 << 20)); // 8 MB
    unsigned short* Cv  = (unsigned short*)(ws + (size_t)(32 << 20)); // 8 MB
    unsigned short* Vpt = (unsigned short*)(ws + (size_t)(40 << 20)); // 8 MB
    float* mod  = (float*)(ws + (size_t)(48 << 20));
    float* mod2 = mod + 1024;
    float* posc = mod2 + 1024;
    float* poss = posc + 2048;
    float* out  = (float*)d_out;

    convert_x_kernel<<<4096, 256, 0, stream>>>(x, Xb, qp, qa, mod, mod2, posc, poss);
    transpose_w_kernel<<<dim3(16, 16, 4), 256, 0, stream>>>(Wq, Wk, Wv, Wo, Wt);
    gemm_kernel<<<dim3(32, 8, 3), 256, 0, stream>>>(Xb, Wt, Cq, out, 0);   // -> Cq,Ck,Cv
    vmod_shift<<<dim3(32, 32), 256, 0, stream>>>(Cv, Vpt, mod);
    attn_kernel<<<dim3(32, 16), 256, 0, stream>>>(Cq, Ck, Vpt, Xb /*Ob*/, mod2, posc, poss);
    gemm_kernel<<<dim3(32, 8, 1), 256, 0, stream>>>(Xb, Wt, Cq, out, 3);   // O-proj -> out
}